// Round 15
// baseline (1150.169 us; speedup 1.0000x reference)
//
#include <hip/hip_runtime.h>
#include <hip/hip_cooperative_groups.h>

namespace cg = cooperative_groups;

// ---------------------------------------------------------------------------
// DualRealConvTasNet — round 15: round 14 + register-prefetch pipeline in
// conv_mfma (issue next c0's global loads into VGPRs before the MFMA phase;
// write regs->LDS after the trailing barrier). Hides the ~300-900 cyc
// L2/L3 staging latency behind 48 MFMAs/iter at unchanged LDS/occupancy.
// TCN frozen from round 14 (absmax 0.009765625 stable, no release fence).
// ---------------------------------------------------------------------------

typedef unsigned short u16;
typedef __attribute__((ext_vector_type(8))) short bf16x8_t;
typedef __attribute__((ext_vector_type(4))) float f32x4_t;

#define ST    2064
#define HALO  8
#define TR    2064
#define RHALO 8

// ---- workspace layout ----
#define U_F0H   0ULL
#define U_F1H   8454144ULL
#define F_F2    8454144ULL
#define F_D2    0ULL
#define U_YH    33816576ULL
#define U_D1H   50724864ULL
#define F_O     33816576ULL
#define F_G0    35930112ULL
#define F_G1    36458496ULL
#define F_W     36986880ULL
#define W_MGIN  0ULL
#define W_MGOUT 65536ULL
#define W_W1T   196608ULL
#define W_WSUMT 294912ULL
#define W_BSUM  393216ULL
#define U_WB    74766336ULL
#define F_FLAG  38956032ULL
#define F_G2    38964224ULL
#define F_G3    39492608ULL

__device__ __forceinline__ float prelu_f(float x, float a) { return x >= 0.f ? x : a * x; }
__device__ __forceinline__ u16 f2b(float f) {
    unsigned u = __float_as_uint(f);
    return (u16)((u + 0x7FFF + ((u >> 16) & 1)) >> 16);
}

// ---------------------------------------------------------------------------
// Weight prep. task = blockIdx.y (0..8).
// ---------------------------------------------------------------------------
__global__ __launch_bounds__(256) void prep_weights(
    const float* __restrict__ ew1, const float* __restrict__ ew2,
    const float* __restrict__ dw1, const float* __restrict__ dw2,
    const float* __restrict__ mgin_w, const float* __restrict__ mgout_w,
    const float* __restrict__ bw1, const float* __restrict__ brw,
    const float* __restrict__ brb, const float* __restrict__ bsw,
    const float* __restrict__ bsb, float* __restrict__ wsf, u16* __restrict__ wsb)
{
    const int task = blockIdx.y;
    const int idx  = blockIdx.x * 256 + threadIdx.x;
    const int stride = gridDim.x * 256;
    if (task < 4) {
        const float* src = (task == 0) ? ew1 : (task == 1) ? ew2 : (task == 2) ? dw1 : dw2;
        u16* dst = wsb + U_WB + (size_t)task * 786432ULL;
        const bool dec = (task >= 2);
        for (int n = idx; n < 786432; n += stride) {
            int j = n >> 18, o = (n >> 9) & 511, c = n & 511;
            float v = dec ? src[(size_t)c * 1536 + o * 3 + (2 - j)]
                          : src[(size_t)o * 1536 + c * 3 + j];
            dst[n] = f2b(v);
        }
    } else if (task == 4) {
        float* dst = wsf + F_W + W_MGIN;
        for (int n = idx; n < 65536; n += stride) {
            int o = n & 127, c = n >> 7;
            dst[n] = mgin_w[(size_t)o * 512 + c];
        }
    } else if (task == 5) {
        float* dst = wsf + F_W + W_MGOUT;
        for (int n = idx; n < 131072; n += stride) {
            int m = n & 1023, c = n >> 10;
            dst[n] = mgout_w[(size_t)m * 128 + c];
        }
    } else if (task == 6) {
        float* dst = wsf + F_W + W_W1T;
        for (int n = idx; n < 98304; n += stride) {
            int cc = n & 31, C = (n >> 5) & 127, i = n >> 12;
            dst[n] = bw1[(size_t)i * 4096 + cc * 128 + C];
        }
    } else if (task == 7) {
        float* dst = wsf + F_W + W_WSUMT;
        for (int n = idx; n < 98304; n += stride) {
            int C = n & 127, cc = (n >> 7) & 31, i = n >> 12;
            float v = bsw[(size_t)i * 4096 + C * 32 + cc];
            if (i < 23) v += brw[(size_t)i * 4096 + C * 32 + cc];
            dst[n] = v;
        }
    } else {
        float* dst = wsf + F_W + W_BSUM;
        for (int n = idx; n < 3072; n += stride) {
            int i = n >> 7;
            float v = bsb[n];
            if (i < 23) v += brb[n];
            dst[n] = v;
        }
    }
}

// ---------------------------------------------------------------------------
// Zero pad rows of all four bf16 tensors. grid (16, 69, 4).
// ---------------------------------------------------------------------------
__global__ __launch_bounds__(256) void zero_pads_all(
    u16* __restrict__ f0h, u16* __restrict__ f1h,
    u16* __restrict__ yh, u16* __restrict__ d1h)
{
    const int z = blockIdx.z;
    u16* base; int Treal, nb;
    if (z == 0)      { base = f0h; Treal = 1999; nb = 8; }
    else if (z == 1) { base = f1h; Treal = 1997; nb = 8; }
    else if (z == 2) { base = yh;  Treal = 1995; nb = 16; }
    else             { base = d1h; Treal = 1997; nb = 16; }
    if ((int)blockIdx.x >= nb) return;
    const int prcnt = TR - Treal;
    const int pr = blockIdx.y;
    if (pr >= prcnt) return;
    const int row = (pr < RHALO) ? pr : (Treal + pr);
    ((unsigned*)(base + ((size_t)blockIdx.x * TR + row) * 512))[threadIdx.x] = 0u;
}

// ---------------------------------------------------------------------------
// Encoder conv0: 1->512, k16 s8 -> bf16 [t][c]. grid (8, 64, 8)
// ---------------------------------------------------------------------------
__global__ __launch_bounds__(256) void enc0_kernel(
    const float* __restrict__ xr, const float* __restrict__ xi,
    const float* __restrict__ w0, u16* __restrict__ f0h)
{
    const int t  = blockIdx.x * 256 + threadIdx.x;
    const int c0 = blockIdx.y * 8;
    const int b  = blockIdx.z;
    if (t >= 1999) return;
    const float* x = (b < 4) ? (xr + (size_t)b * 16000) : (xi + (size_t)(b - 4) * 16000);
    float xv[16];
    const int base = t * 8;
#pragma unroll
    for (int k = 0; k < 16; k++) xv[k] = x[base + k];
    union { u16 u[8]; uint4 v; } p;
#pragma unroll
    for (int cq = 0; cq < 8; cq++) {
        const float* w = w0 + (size_t)(c0 + cq) * 16;
        float acc = 0.f;
#pragma unroll
        for (int k = 0; k < 16; k++) acc = fmaf(xv[k], w[k], acc);
        p.u[cq] = f2b(acc);
    }
    *(uint4*)&f0h[((size_t)b * TR + RHALO + t) * 512 + c0] = p.v;
}

// ---------------------------------------------------------------------------
// bf16 MFMA conv3 (+PReLU), register-prefetch pipelined staging.
// Tile 128o x 128t, BK=32, j inner. grid (16,4,B)
// OUTF32=0: bf16 [t][c] out via LDS-transpose epilogue.
// OUTF32=1: fp32 [c][t] out.
// ---------------------------------------------------------------------------
template <int JOFF, int OUTF32>
__global__ __launch_bounds__(256) void conv_mfma(
    const u16* __restrict__ in, u16* __restrict__ out16, float* __restrict__ out32,
    const u16* __restrict__ wM, const float* __restrict__ alpha_p, int Tout)
{
    __shared__ __align__(16) u16 smem[20560];
    u16* As = smem;            // [j][128 o][40]
    u16* Bs = smem + 15360;    // [130 t][40]
    const int tid  = threadIdx.x;
    const int t0   = blockIdx.x * 128;
    const int ob   = blockIdx.y * 128;
    const int b    = blockIdx.z;
    const int l15  = tid & 15;
    const int quad = (tid >> 4) & 3;
    const int wave = tid >> 6;
    const int wm   = (wave & 1) * 64;
    const int wn   = (wave >> 1) * 64;
    const u16* inb = in + (size_t)b * TR * 512;

    uint4 pa[6], pb[3];

    auto load_stage = [&](int c0) {
#pragma unroll
        for (int r = 0; r < 6; r++) {
            int v = tid + r * 256;
            int j = v >> 9, rr = (v >> 2) & 127, seg = v & 3;
            pa[r] = *(const uint4*)&wM[((size_t)(j * 512 + ob + rr)) * 512 + c0 + seg * 8];
        }
#pragma unroll
        for (int r = 0; r < 3; r++) {
            int v = tid + r * 256;
            if (v < 520) {
                int rr = v >> 2, seg = v & 3;
                int row = RHALO + t0 + JOFF + rr;
                pb[r] = *(const uint4*)&inb[(size_t)row * 512 + c0 + seg * 8];
            }
        }
    };
    auto store_stage = [&]() {
#pragma unroll
        for (int r = 0; r < 6; r++) {
            int v = tid + r * 256;
            int j = v >> 9, rr = (v >> 2) & 127, seg = v & 3;
            *(uint4*)&As[j * 5120 + rr * 40 + seg * 8] = pa[r];
        }
#pragma unroll
        for (int r = 0; r < 3; r++) {
            int v = tid + r * 256;
            if (v < 520) {
                int rr = v >> 2, seg = v & 3;
                *(uint4*)&Bs[rr * 40 + seg * 8] = pb[r];
            }
        }
    };

    f32x4_t acc[4][4];
#pragma unroll
    for (int i = 0; i < 4; i++)
#pragma unroll
        for (int k = 0; k < 4; k++) acc[i][k] = (f32x4_t){0.f, 0.f, 0.f, 0.f};

    load_stage(0);
    store_stage();

    for (int c0 = 0; c0 < 512; c0 += 32) {
        const bool more = (c0 + 32 < 512);
        __syncthreads();                 // staged tile visible
        if (more) load_stage(c0 + 32);   // prefetch next tile into VGPRs
#pragma unroll
        for (int j = 0; j < 3; j++) {
            bf16x8_t aw[4], bi[4];
#pragma unroll
            for (int mf = 0; mf < 4; mf++)
                aw[mf] = *(const bf16x8_t*)&As[j * 5120 + (wm + mf * 16 + l15) * 40 + quad * 8];
#pragma unroll
            for (int nf = 0; nf < 4; nf++)
                bi[nf] = *(const bf16x8_t*)&Bs[(wn + nf * 16 + l15 + j) * 40 + quad * 8];
#pragma unroll
            for (int mf = 0; mf < 4; mf++)
#pragma unroll
                for (int nf = 0; nf < 4; nf++) {
                    if (OUTF32)
                        acc[mf][nf] = __builtin_amdgcn_mfma_f32_16x16x32_bf16(
                            bi[nf], aw[mf], acc[mf][nf], 0, 0, 0);
                    else
                        acc[mf][nf] = __builtin_amdgcn_mfma_f32_16x16x32_bf16(
                            aw[mf], bi[nf], acc[mf][nf], 0, 0, 0);
                }
        }
        __syncthreads();                 // all LDS reads done
        if (more) store_stage();         // vmcnt wait lands here, behind MFMAs
    }

    const float alpha = *alpha_p;
    if (!OUTF32) {
        u16* tile = smem;   // [128 t][136 c]
#pragma unroll
        for (int mf = 0; mf < 4; mf++)
#pragma unroll
            for (int nf = 0; nf < 4; nf++) {
                const int t_loc = wn + nf * 16 + l15;
                const int c_loc = wm + mf * 16 + quad * 4;
                f32x4_t a = acc[mf][nf];
                ushort4 s;
                s.x = f2b(prelu_f(a.x, alpha));
                s.y = f2b(prelu_f(a.y, alpha));
                s.z = f2b(prelu_f(a.z, alpha));
                s.w = f2b(prelu_f(a.w, alpha));
                *(ushort4*)&tile[t_loc * 136 + c_loc] = s;
            }
        __syncthreads();
        for (int v = tid; v < 2048; v += 256) {
            const int row = v >> 4, seg = v & 15;
            const int t = t0 + row;
            if (t < Tout)
                *(uint4*)&out16[((size_t)b * TR + RHALO + t) * 512 + ob + seg * 8] =
                    *(const uint4*)&tile[row * 136 + seg * 8];
        }
    } else {
#pragma unroll
        for (int mf = 0; mf < 4; mf++)
#pragma unroll
            for (int nf = 0; nf < 4; nf++) {
                const int o  = ob + wm + mf * 16 + l15;
                const int tb = t0 + wn + nf * 16 + quad * 4;
                f32x4_t a = acc[mf][nf];
                float v0 = prelu_f(a.x, alpha), v1 = prelu_f(a.y, alpha);
                float v2 = prelu_f(a.z, alpha), v3 = prelu_f(a.w, alpha);
                float* p = out32 + ((size_t)(b * 512 + o)) * ST + HALO + tb;
                if (tb + 3 < Tout) {
                    *(float4*)p = make_float4(v0, v1, v2, v3);
                } else {
                    if (tb + 0 < Tout) p[0] = v0;
                    if (tb + 1 < Tout) p[1] = v1;
                    if (tb + 2 < Tout) p[2] = v2;
                    if (tb + 3 < Tout) p[3] = v3;
                }
            }
    }
}

// ---------------------------------------------------------------------------
// mg_in: o = mg_in_w @ f2 + b (512->128), fused g0 = prelu(pw1_0(o)).
// grid (32, 8)
// ---------------------------------------------------------------------------
__global__ __launch_bounds__(256) void mgin_kernel(
    const float* __restrict__ f2, float* __restrict__ o_buf, float* __restrict__ g_out,
    const float* __restrict__ wT, const float* __restrict__ bias,
    const float* __restrict__ w1T0, const float* __restrict__ b1_0,
    const float* __restrict__ a1_0)
{
    __shared__ float Bs[16][64];
    __shared__ float As[16][128];
    __shared__ float o_lds[128][64];
    const int tid = threadIdx.x;
    const int t0  = blockIdx.x * 64;
    const int b   = blockIdx.y;
    const float* f2b_ = f2 + (size_t)b * 512 * ST + HALO + t0;

    float acc[8][4];
#pragma unroll
    for (int i = 0; i < 8; i++)
#pragma unroll
        for (int k = 0; k < 4; k++) acc[i][k] = 0.f;
    const int tx = tid & 15, ty = tid >> 4;

    for (int c0 = 0; c0 < 512; c0 += 16) {
        {
            int c = tid >> 4, p = tid & 15;
            *(float4*)(&Bs[c][p * 4]) = *(const float4*)(f2b_ + (size_t)(c0 + c) * ST + p * 4);
        }
#pragma unroll
        for (int r = 0; r < 2; r++) {
            int n4 = tid + r * 256;
            int c = n4 >> 5, m4 = n4 & 31;
            *(float4*)(&As[c][m4 * 4]) = *(const float4*)(wT + (size_t)(c0 + c) * 128 + m4 * 4);
        }
        __syncthreads();
#pragma unroll 2
        for (int c = 0; c < 16; c++) {
            float4 bv = *(const float4*)(&Bs[c][tx * 4]);
            float a[8];
            *(float4*)(&a[0]) = *(const float4*)(&As[c][ty * 8]);
            *(float4*)(&a[4]) = *(const float4*)(&As[c][ty * 8 + 4]);
#pragma unroll
            for (int oi = 0; oi < 8; oi++) {
                acc[oi][0] = fmaf(a[oi], bv.x, acc[oi][0]);
                acc[oi][1] = fmaf(a[oi], bv.y, acc[oi][1]);
                acc[oi][2] = fmaf(a[oi], bv.z, acc[oi][2]);
                acc[oi][3] = fmaf(a[oi], bv.w, acc[oi][3]);
            }
        }
        __syncthreads();
    }

    const int tb = t0 + tx * 4;
#pragma unroll
    for (int oi = 0; oi < 8; oi++) {
        const int o = ty * 8 + oi;
        const float bo = bias[o];
        float vv[4];
#pragma unroll
        for (int kk = 0; kk < 4; kk++) vv[kk] = acc[oi][kk] + bo;
        *(float4*)(&o_lds[o][tx * 4]) = make_float4(vv[0], vv[1], vv[2], vv[3]);
        float* orow = o_buf + (size_t)(b * 128 + o) * ST + HALO + tb;
        if (tb + 3 < 1995) {
            *(float4*)orow = make_float4(vv[0], vv[1], vv[2], vv[3]);
        } else {
#pragma unroll
            for (int kk = 0; kk < 4; kk++)
                if (tb + kk < 1995) orow[kk] = vv[kk];
        }
    }
    __syncthreads();

    const int t = tid & 63, cg_ = tid >> 6;
    const float a1 = *a1_0;
    float acc2[8];
#pragma unroll
    for (int q = 0; q < 8; q++) acc2[q] = b1_0[cg_ * 8 + q];
    for (int C = 0; C < 128; C++) {
        const float ov = o_lds[C][t];
        const float4* wr = (const float4*)(w1T0 + (size_t)C * 32 + cg_ * 8);
        float4 w0 = wr[0], w1 = wr[1];
        acc2[0] = fmaf(w0.x, ov, acc2[0]); acc2[1] = fmaf(w0.y, ov, acc2[1]);
        acc2[2] = fmaf(w0.z, ov, acc2[2]); acc2[3] = fmaf(w0.w, ov, acc2[3]);
        acc2[4] = fmaf(w1.x, ov, acc2[4]); acc2[5] = fmaf(w1.y, ov, acc2[5]);
        acc2[6] = fmaf(w1.z, ov, acc2[6]); acc2[7] = fmaf(w1.w, ov, acc2[7]);
    }
    const int tt = t0 + t;
    if (tt < 1995) {
#pragma unroll
        for (int q = 0; q < 8; q++)
            g_out[(size_t)(b * 32 + cg_ * 8 + q) * ST + HALO + tt] = prelu_f(acc2[q], a1);
    }
}

// ---------------------------------------------------------------------------
// Fused TCN (frozen from round 14): LDS-resident g ping-pong, halo-only
// global traffic, relaxed poll + acquire fence; publish after vmcnt drain.
// ---------------------------------------------------------------------------
__device__ __forceinline__ void poll_acquire(const unsigned* flags, int b, int j,
                                             int k, unsigned target)
{
    int lo = j - k; if (lo < 0) lo = 0;
    int hi = j + k; if (hi > 31) hi = 31;
    for (int n = lo; n <= hi; n++) {
        if (n == j) continue;
        const unsigned* p = flags + ((b << 5) + n) * 16;
        while (__hip_atomic_load(p, __ATOMIC_RELAXED, __HIP_MEMORY_SCOPE_AGENT) < target)
            __builtin_amdgcn_s_sleep(2);
    }
    __builtin_amdgcn_fence(__ATOMIC_ACQUIRE, "agent");
}

__device__ __forceinline__ void store_pair_agent(float* dst, int trel, float v0, float v1)
{
    if (trel + 1 < 1995) {
        unsigned long long raw =
            ((unsigned long long)__float_as_uint(v1) << 32) | __float_as_uint(v0);
        __hip_atomic_store((unsigned long long*)dst, raw,
                           __ATOMIC_RELAXED, __HIP_MEMORY_SCOPE_AGENT);
    } else if (trel < 1995) {
        __hip_atomic_store(dst, v0, __ATOMIC_RELAXED, __HIP_MEMORY_SCOPE_AGENT);
    }
}

__global__ __launch_bounds__(512) void tcn_fused(
    float* __restrict__ g0, float* __restrict__ g1,
    float* __restrict__ g2, float* __restrict__ g3,
    float* __restrict__ o_buf,
    const float* __restrict__ dw_all, const float* __restrict__ db_all,
    const float* __restrict__ a2_all,
    const float* __restrict__ wsumT_all, const float* __restrict__ bsum_all,
    const float* __restrict__ w1T_all, const float* __restrict__ b1_all,
    const float* __restrict__ a1_all, unsigned* __restrict__ wflag)
{
    __shared__ __align__(16) float w_lds[8192];
    __shared__ __align__(16) float h_lds[32 * 68];
    __shared__ __align__(16) float o_lds[128 * 68];
    __shared__ __align__(16) float g_lds[2][32 * 68];
    __shared__ __align__(16) float halo_lds[32 * 260];
    const int tid = threadIdx.x;
    const int blk = blockIdx.x;
    const int b   = blk & 7;
    const int jt  = blk >> 3;
    const int t0  = jt * 64;
    float* gb[4] = { g0, g1, g2, g3 };

#pragma unroll
    for (int k = 0; k < 4; k++) {
        int n = tid + k * 512;
        int C = n >> 4, seg = n & 15;
        *(float4*)&o_lds[C * 68 + seg * 4] =
            *(const float4*)&o_buf[((size_t)(b * 128 + C)) * ST + HALO + t0 + seg * 4];
    }
    {
        int cc = tid >> 4, seg = tid & 15;
        *(float4*)&g_lds[0][cc * 68 + seg * 4] =
            *(const float4*)&g0[((size_t)(b * 32 + cc)) * ST + HALO + t0 + seg * 4];
    }

    for (int i = 0; i < 24; i++) {
        const int dil  = 1 << (i & 7);
        const int dil2 = (dil < 2) ? 2 : dil;
        const int k_rd = (dil > 64) ? 2 : 1;
        const float* gin_g = gb[i & 3];
        float* gout_g      = gb[(i + 1) & 3];
        float* gin_lds  = g_lds[i & 1];
        float* gout_lds = g_lds[(i + 1) & 1];

        {
            const float* wsum = wsumT_all + (size_t)i * 4096;
#pragma unroll
            for (int k = 0; k < 2; k++) {
                int n = tid + k * 512;
                *(float4*)&w_lds[n * 4] = *(const float4*)&wsum[n * 4];
            }
            if (i < 23) {
                const float* w1 = w1T_all + (size_t)(i + 1) * 4096;
#pragma unroll
                for (int k = 0; k < 2; k++) {
                    int n = tid + k * 512;
                    *(float4*)&w_lds[4096 + n * 4] = *(const float4*)&w1[n * 4];
                }
            }
        }

        if (i > 0 && tid == 0) poll_acquire(wflag, b, jt, k_rd, (unsigned)i);
        __syncthreads();

        // halo load: dsh covers dil2 up to 128 (7 bits) — r13 fix.
        {
            const int dsh = (dil2 >= 128) ? 7 : (dil2 >= 64) ? 6 : (dil2 >= 32) ? 5
                          : (dil2 >= 16) ? 4 : (dil2 >= 8) ? 3 : (dil2 >= 4) ? 2 : 1;
            const int total = 32 << dsh;
            for (int n = tid; n < total; n += 512) {
                const int cc = n >> dsh;
                const int pi = n & (dil2 - 1);
                const int hc = pi * 2;
                const int tg = (hc < dil2) ? (t0 - dil2 + hc) : (t0 + 64 + hc - dil2);
                float v0 = 0.f, v1 = 0.f;
                const float* src = gin_g + ((size_t)(b * 32 + cc)) * ST + HALO + tg;
                if (tg >= 0 && tg + 1 < 1995) {
                    unsigned long long raw = __hip_atomic_load(
                        (const unsigned long long*)src,
                        __ATOMIC_RELAXED, __HIP_MEMORY_SCOPE_AGENT);
                    v0 = __uint_as_float((unsigned)raw);
                    v1 = __uint_as_float((unsigned)(raw >> 32));
                } else {
                    if (tg >= 0 && tg < 1995)
                        v0 = __hip_atomic_load(src, __ATOMIC_RELAXED,
                                               __HIP_MEMORY_SCOPE_AGENT);
                    if (tg + 1 >= 0 && tg + 1 < 1995)
                        v1 = __hip_atomic_load(src + 1, __ATOMIC_RELAXED,
                                               __HIP_MEMORY_SCOPE_AGENT);
                }
                halo_lds[cc * 260 + hc]     = v0;
                halo_lds[cc * 260 + hc + 1] = v1;
            }
        }
        __syncthreads();

        {
            const float a2 = a2_all[i];
            const int t = tid & 63, cc0 = (tid >> 6) * 4;
            const int tt = t0 + t;
#pragma unroll
            for (int q = 0; q < 4; q++) {
                const int cc = cc0 + q;
                const float w0 = dw_all[i * 96 + cc * 3 + 0];
                const float w1v = dw_all[i * 96 + cc * 3 + 1];
                const float w2 = dw_all[i * 96 + cc * 3 + 2];
                const float ctr = gin_lds[cc * 68 + t];
                float lo = 0.f, hi = 0.f;
                const int tm = tt - dil;
                if (tm >= 0)
                    lo = (tm >= t0) ? gin_lds[cc * 68 + (tm - t0)]
                                    : halo_lds[cc * 260 + (tm - t0 + dil2)];
                const int tp = tt + dil;
                if (tp < 1995)
                    hi = (tp < t0 + 64) ? gin_lds[cc * 68 + (tp - t0)]
                                        : halo_lds[cc * 260 + (dil2 + tp - t0 - 64)];
                float s = db_all[i * 32 + cc] + w1v * ctr;
                s = fmaf(w0, lo, s);
                s = fmaf(w2, hi, s);
                h_lds[cc * 68 + t] = prelu_f(s, a2);
            }
        }
        __syncthreads();

        {
            const int c4 = tid & 31, t4 = tid >> 5;
            float s[4][4];
#pragma unroll
            for (int ci = 0; ci < 4; ci++)
#pragma unroll
                for (int tj = 0; tj < 4; tj++) s[ci][tj] = 0.f;
            for (int cc = 0; cc < 32; cc++) {
                float4 w4 = *(const float4*)&w_lds[cc * 128 + c4 * 4];
                float4 h4 = *(const float4*)&h_lds[cc * 68 + t4 * 4];
                const float wv[4] = {w4.x, w4.y, w4.z, w4.w};
                const float hv[4] = {h4.x, h4.y, h4.z, h4.w};
#pragma unroll
                for (int ci = 0; ci < 4; ci++)
#pragma unroll
                    for (int tj = 0; tj < 4; tj++)
                        s[ci][tj] = fmaf(wv[ci], hv[tj], s[ci][tj]);
            }
#pragma unroll
            for (int ci = 0; ci < 4; ci++) {
                const int C = c4 * 4 + ci;
                const float bs = bsum_all[i * 128 + C];
                float4 ov = *(float4*)&o_lds[C * 68 + t4 * 4];
                ov.x += s[ci][0] + bs;
                ov.y += s[ci][1] + bs;
                ov.z += s[ci][2] + bs;
                ov.w += s[ci][3] + bs;
                *(float4*)&o_lds[C * 68 + t4 * 4] = ov;
            }
        }

        if (i == 23) break;
        __syncthreads();

        {
            const int cc = tid & 31, tq = tid >> 5;
            const float a1 = a1_all[i + 1];
            const float b1v = b1_all[(i + 1) * 32 + cc];
            float acc2[4] = {b1v, b1v, b1v, b1v};
            for (int C = 0; C < 128; C++) {
                const float wv = w_lds[4096 + C * 32 + cc];
                float4 o4 = *(const float4*)&o_lds[C * 68 + tq * 4];
                acc2[0] = fmaf(wv, o4.x, acc2[0]);
                acc2[1] = fmaf(wv, o4.y, acc2[1]);
                acc2[2] = fmaf(wv, o4.z, acc2[2]);
                acc2[3] = fmaf(wv, o4.w, acc2[3]);
            }
#pragma unroll
            for (int kk = 0; kk < 4; kk++)
                gout_lds[cc * 68 + tq * 4 + kk] = prelu_f(acc2[kk], a1);
        }
        __syncthreads();

        {
            const int dnext = 1 << ((i + 1) & 7);
            int md2 = (dnext > 64) ? 64 : dnext;
            if (md2 < 2) md2 = 2;
            if (md2 >= 64) {
                for (int n = tid; n < 1024; n += 512) {
                    const int cc = n >> 5, pi = n & 31;
                    const int lt = pi * 2;
                    float* dst = gout_g + ((size_t)(b * 32 + cc)) * ST + HALO + t0 + lt;
                    store_pair_agent(dst, t0 + lt,
                                     gout_lds[cc * 68 + lt], gout_lds[cc * 68 + lt + 1]);
                }
            } else {
                const int msh = (md2 >= 32) ? 5 : (md2 >= 16) ? 4 : (md2 >= 8) ? 3
                              : (md2 >= 4) ? 2 : 1;
                const int total = 32 << msh;
                for (int n = tid; n < total; n += 512) {
                    const int cc = n >> msh;
                    const int pi = n & (md2 - 1);
                    const int hc = pi * 2;
                    const int lt = (hc < md2) ? hc : (64 - 2 * md2 + hc);
                    float* dst = gout_g + ((size_t)(b * 32 + cc)) * ST + HALO + t0 + lt;
                    store_pair_agent(dst, t0 + lt,
                                     gout_lds[cc * 68 + lt], gout_lds[cc * 68 + lt + 1]);
                }
            }
        }
        __syncthreads();   // vmcnt drain: write-through stores acked at coherence point

        if (tid == 0)
            __hip_atomic_store(&wflag[((b << 5) + jt) * 16], (unsigned)(i + 1),
                               __ATOMIC_RELAXED, __HIP_MEMORY_SCOPE_AGENT);
    }

    __syncthreads();
#pragma unroll
    for (int k = 0; k < 4; k++) {
        int n = tid + k * 512;
        int C = n >> 4, seg = n & 15;
        *(float4*)&o_buf[((size_t)(b * 128 + C)) * ST + HALO + t0 + seg * 4] =
            *(const float4*)&o_lds[C * 68 + seg * 4];
    }
}

// ---------------------------------------------------------------------------
// mask + multiply -> y bf16 [t][c] via LDS transpose. grid (32, 4, 8)
// ---------------------------------------------------------------------------
__global__ __launch_bounds__(256) void mask_kernel(
    const float* __restrict__ o_buf, const float* __restrict__ f2, u16* __restrict__ yh,
    const float* __restrict__ wT, const float* __restrict__ mb,
    const float* __restrict__ a_out_p)
{
    __shared__ __align__(16) char smem[65536];
    float (*o_lds)[64]  = (float (*)[64])smem;
    float (*w_lds)[256] = (float (*)[256])(smem + 32768);
    u16* tile = (u16*)smem;

    const int tid = threadIdx.x;
    const int t0  = blockIdx.x * 64;
    const int m0  = blockIdx.y * 256;
    const int b   = blockIdx.z;
    const float ao = *a_out_p;

#pragma unroll
    for (int r = 0; r < 8; r++) {
        int n4 = tid + r * 256;
        int C = n4 >> 4, p = n4 & 15;
        float4 v = *(const float4*)(o_buf + (size_t)(b * 128 + C) * ST + HALO + t0 + p * 4);
        v.x = prelu_f(v.x, ao); v.y = prelu_f(v.y, ao);
        v.z = prelu_f(v.z, ao); v.w = prelu_f(v.w, ao);
        *(float4*)(&o_lds[C][p * 4]) = v;
    }

    float acc[16][4];
#pragma unroll
    for (int i = 0; i < 16; i++)
#pragma unroll
        for (int k = 0; k < 4; k++) acc[i][k] = 0.f;
    const int tx = tid & 15, my = tid >> 4;

    for (int C0 = 0; C0 < 128; C0 += 32) {
#pragma unroll
        for (int r = 0; r < 8; r++) {
            int n4 = tid + r * 256;
            int c = n4 >> 6, m4 = n4 & 63;
            *(float4*)(&w_lds[c][m4 * 4]) =
                *(const float4*)(wT + (size_t)(C0 + c) * 1024 + m0 + m4 * 4);
        }
        __syncthreads();
#pragma unroll 2
        for (int c = 0; c < 32; c++) {
            float4 bv = *(const float4*)(&o_lds[C0 + c][tx * 4]);
            float a[16];
            *(float4*)(&a[0])  = *(const float4*)(&w_lds[c][my * 16 + 0]);
            *(float4*)(&a[4])  = *(const float4*)(&w_lds[c][my * 16 + 4]);
            *(float4*)(&a[8])  = *(const float4*)(&w_lds[c][my * 16 + 8]);
            *(float4*)(&a[12]) = *(const float4*)(&w_lds[c][my * 16 + 12]);
#pragma unroll
            for (int mm = 0; mm < 16; mm++) {
                acc[mm][0] = fmaf(a[mm], bv.x, acc[mm][0]);
                acc[mm][1] = fmaf(a[mm], bv.y, acc[mm][1]);
                acc[mm][2] = fmaf(a[mm], bv.z, acc[mm][2]);
                acc[mm][3] = fmaf(a[mm], bv.w, acc[mm][3]);
            }
        }
        __syncthreads();
    }

    const int tb = t0 + tx * 4;
#pragma unroll
    for (int mm = 0; mm < 16; mm++) {
        const int mi = m0 + my * 16 + mm;
        const float bb = mb[mi];
        const int F = mi & 511;
        const float* f2row = f2 + (size_t)(b * 512 + F) * ST + HALO + tb;
#pragma unroll
        for (int kk = 0; kk < 4; kk++) {
            const float mval = 1.f / (1.f + __expf(-(acc[mm][kk] + bb)));
            acc[mm][kk] = mval * f2row[kk];
        }
    }
#pragma unroll
    for (int kk = 0; kk < 4; kk++) {
        const int row = tx * 4 + kk;
#pragma unroll
        for (int half = 0; half < 2; half++) {
            union { u16 u[8]; uint4 v; } p;
#pragma unroll
            for (int q = 0; q < 8; q++) p.u[q] = f2b(acc[half * 8 + q][kk]);
            *(uint4*)&tile[row * 280 + my * 16 + half * 8] = p.v;
        }
    }
    __syncthreads();
    const int F0 = m0 & 511, sIdx = m0 >> 9;
    u16* ybase = yh + ((size_t)(b * 2 + sIdx) * TR) * 512;
    for (int i = tid; i < 2048; i += 256) {
        const int row = i >> 5, seg = i & 31;
        const int t = t0 + row;
        if (t < 1995)
            *(uint4*)&ybase[(size_t)(RHALO + t) * 512 + F0 + seg * 8] =
                *(const uint4*)&tile[row * 280 + seg * 8];
    }
}

// ---------------------------------------------------------------------------
// Decoder tconv3: 512->1, k16 s8. OOB taps read as 0. grid (63, 16)
// ---------------------------------------------------------------------------
__global__ __launch_bounds__(256) void dec3_kernel(
    const float* __restrict__ d2, const float* __restrict__ w3, float* __restrict__ out)
{
    __shared__ float tile[512][34];
    const int tid = threadIdx.x;
    const int bb  = blockIdx.y;
    const int tau0 = blockIdx.x * 256;
    const int tbase = (tau0 >> 3) - 1;
    const float* src = d2 + (size_t)bb * 512 * ST + HALO + tbase;
    for (int n = tid; n < 512 * 34; n += 256) {
        int o = n / 34, i = n % 34;
        const int tg = tbase + i;
        tile[o][i] = (tg >= 0 && tg < 1999) ? src[(size_t)o * ST + i] : 0.f;
    }
    __syncthreads();

    const int tau = tau0 + tid;
    if (tau >= 16000) return;
    const int k1 = tau & 7;
    const int t1l = (tid >> 3) + 1;
    float acc = 0.f;
#pragma unroll 8
    for (int o = 0; o < 512; o++) {
        acc = fmaf(tile[o][t1l],     w3[o * 16 + k1],     acc);
        acc = fmaf(tile[o][t1l - 1], w3[o * 16 + 8 + k1], acc);
    }
    const int p = bb >> 1, s = bb & 1;
    out[(size_t)(p * 2 + s) * 16000 + tau] = acc;
}

// ---------------------------------------------------------------------------
extern "C" void kernel_launch(void* const* d_in, const int* in_sizes, int n_in,
                              void* d_out, int out_size, void* d_ws, size_t ws_size,
                              hipStream_t stream)
{
    (void)in_sizes; (void)n_in; (void)out_size; (void)ws_size;
    float* ws  = (float*)d_ws;
    u16*   wsu = (u16*)d_ws;
    const float* x_real   = (const float*)d_in[0];
    const float* x_imag   = (const float*)d_in[1];
    const float* enc_w0   = (const float*)d_in[2];
    const float* enc_w1   = (const float*)d_in[3];
    const float* enc_w2   = (const float*)d_in[4];
    const float* enc_a    = (const float*)d_in[5];
    const float* mg_in_w  = (const float*)d_in[6];
    const float* mg_in_b  = (const float*)d_in[7];
    const float* blk_w1   = (const float*)d_in[8];
    const float* blk_b1   = (const float*)d_in[9];
    const float* blk_a1   = (const float*)d_in[10];
    const float* blk_dw   = (const float*)d_in[11];
    const float* blk_db   = (const float*)d_in[12];
    const float* blk_a2   = (const float*)d_in[13];
    const float* blk_rw   = (const float*)d_in[14];
    const float* blk_rb   = (const float*)d_in[15];
    const float* blk_sw   = (const float*)d_in[16];
    const float* blk_sb   = (const float*)d_in[17];
    const float* mg_out_a = (const float*)d_in[18];
    const float* mg_out_w = (const float*)d_in[19];
    const float* mg_out_b = (const float*)d_in[20];
    const float* dec_w1   = (const float*)d_in[21];
    const float* dec_w2   = (const float*)d_in[22];
    const float* dec_a    = (const float*)d_in[23];
    const float* dec_w3   = (const float*)d_in[24];
    float* out = (float*)d_out;

    u16*   f0h   = wsu + U_F0H;
    u16*   f1h   = wsu + U_F1H;
    float* f2    = ws  + F_F2;
    float* d2    = ws  + F_D2;
    u16*   yh    = wsu + U_YH;
    u16*   d1h   = wsu + U_D1H;
    float* obuf  = ws  + F_O;
    float* g0    = ws  + F_G0;
    float* g1    = ws  + F_G1;
    float* g2    = ws  + F_G2;
    float* g3    = ws  + F_G3;
    float* WF    = ws  + F_W;
    u16*   WB    = wsu + U_WB;
    unsigned* flags = (unsigned*)(ws + F_FLAG);

    const dim3 blk(256);

    prep_weights<<<dim3(64, 9), blk, 0, stream>>>(enc_w1, enc_w2, dec_w1, dec_w2,
        mg_in_w, mg_out_w, blk_w1, blk_rw, blk_rb, blk_sw, blk_sb, ws, wsu);

    zero_pads_all<<<dim3(16, 69, 4), blk, 0, stream>>>(f0h, f1h, yh, d1h);

    (void)hipMemsetAsync(flags, 0, 4096 * sizeof(unsigned), stream);

    enc0_kernel<<<dim3(8, 64, 8), blk, 0, stream>>>(x_real, x_imag, enc_w0, f0h);

    conv_mfma<0, 0><<<dim3(16, 4, 8), blk, 0, stream>>>(
        f0h, f1h, nullptr, WB + 0 * 786432, enc_a + 0, 1997);
    conv_mfma<0, 1><<<dim3(16, 4, 8), blk, 0, stream>>>(
        f1h, nullptr, f2, WB + 1 * 786432, enc_a + 1, 1995);

    mgin_kernel<<<dim3(32, 8), blk, 0, stream>>>(f2, obuf, g0, WF + W_MGIN, mg_in_b,
        WF + W_W1T, blk_b1, blk_a1);

    {
        const float* dwp   = blk_dw;
        const float* dbp   = blk_db;
        const float* a2p   = blk_a2;
        const float* wsump = WF + W_WSUMT;
        const float* bsump = WF + W_BSUM;
        const float* w1p   = WF + W_W1T;
        const float* b1p   = blk_b1;
        const float* a1p   = blk_a1;
        unsigned* flg = flags;
        void* args[] = { &g0, &g1, &g2, &g3, &obuf,
                         (void*)&dwp, (void*)&dbp, (void*)&a2p,
                         (void*)&wsump, (void*)&bsump, (void*)&w1p,
                         (void*)&b1p, (void*)&a1p, &flg };
        (void)hipLaunchCooperativeKernel((void*)tcn_fused, dim3(256), dim3(512),
                                         args, 0, stream);
    }

    mask_kernel<<<dim3(32, 4, 8), blk, 0, stream>>>(obuf, f2, yh,
        WF + W_MGOUT, mg_out_b, mg_out_a);

    conv_mfma<-2, 0><<<dim3(16, 4, 16), blk, 0, stream>>>(
        yh, d1h, nullptr, WB + 2 * 786432, dec_a + 0, 1997);
    conv_mfma<-2, 1><<<dim3(16, 4, 16), blk, 0, stream>>>(
        d1h, nullptr, d2, WB + 3 * 786432, dec_a + 1, 1999);

    dec3_kernel<<<dim3(63, 16), blk, 0, stream>>>(d2, dec_w3, out);
}

// Round 16
// 951.944 us; speedup vs baseline: 1.2082x; 1.2082x over previous
//
#include <hip/hip_runtime.h>
#include <hip/hip_cooperative_groups.h>

namespace cg = cooperative_groups;

// ---------------------------------------------------------------------------
// DualRealConvTasNet — round 16: exact revert to round 14 (best-known:
// 954.8 µs, absmax 0.009765625 replay-stable).
// r15's register-prefetch conv regressed +195 µs (VGPR pressure/spill);
// r10's NT=8 regressed +50 µs (occupancy). Conv is at its structural
// plateau; TCN frozen (flag sync, LDS-resident g, halo-only traffic).
// ---------------------------------------------------------------------------

typedef unsigned short u16;
typedef __attribute__((ext_vector_type(8))) short bf16x8_t;
typedef __attribute__((ext_vector_type(4))) float f32x4_t;

#define ST    2064
#define HALO  8
#define TR    2064
#define RHALO 8

// ---- workspace layout ----
#define U_F0H   0ULL
#define U_F1H   8454144ULL
#define F_F2    8454144ULL
#define F_D2    0ULL
#define U_YH    33816576ULL
#define U_D1H   50724864ULL
#define F_O     33816576ULL
#define F_G0    35930112ULL
#define F_G1    36458496ULL
#define F_W     36986880ULL
#define W_MGIN  0ULL
#define W_MGOUT 65536ULL
#define W_W1T   196608ULL
#define W_WSUMT 294912ULL
#define W_BSUM  393216ULL
#define U_WB    74766336ULL
#define F_FLAG  38956032ULL
#define F_G2    38964224ULL
#define F_G3    39492608ULL

__device__ __forceinline__ float prelu_f(float x, float a) { return x >= 0.f ? x : a * x; }
__device__ __forceinline__ u16 f2b(float f) {
    unsigned u = __float_as_uint(f);
    return (u16)((u + 0x7FFF + ((u >> 16) & 1)) >> 16);
}

// ---------------------------------------------------------------------------
// Weight prep. task = blockIdx.y (0..8).
// ---------------------------------------------------------------------------
__global__ __launch_bounds__(256) void prep_weights(
    const float* __restrict__ ew1, const float* __restrict__ ew2,
    const float* __restrict__ dw1, const float* __restrict__ dw2,
    const float* __restrict__ mgin_w, const float* __restrict__ mgout_w,
    const float* __restrict__ bw1, const float* __restrict__ brw,
    const float* __restrict__ brb, const float* __restrict__ bsw,
    const float* __restrict__ bsb, float* __restrict__ wsf, u16* __restrict__ wsb)
{
    const int task = blockIdx.y;
    const int idx  = blockIdx.x * 256 + threadIdx.x;
    const int stride = gridDim.x * 256;
    if (task < 4) {
        const float* src = (task == 0) ? ew1 : (task == 1) ? ew2 : (task == 2) ? dw1 : dw2;
        u16* dst = wsb + U_WB + (size_t)task * 786432ULL;
        const bool dec = (task >= 2);
        for (int n = idx; n < 786432; n += stride) {
            int j = n >> 18, o = (n >> 9) & 511, c = n & 511;
            float v = dec ? src[(size_t)c * 1536 + o * 3 + (2 - j)]
                          : src[(size_t)o * 1536 + c * 3 + j];
            dst[n] = f2b(v);
        }
    } else if (task == 4) {
        float* dst = wsf + F_W + W_MGIN;
        for (int n = idx; n < 65536; n += stride) {
            int o = n & 127, c = n >> 7;
            dst[n] = mgin_w[(size_t)o * 512 + c];
        }
    } else if (task == 5) {
        float* dst = wsf + F_W + W_MGOUT;
        for (int n = idx; n < 131072; n += stride) {
            int m = n & 1023, c = n >> 10;
            dst[n] = mgout_w[(size_t)m * 128 + c];
        }
    } else if (task == 6) {
        float* dst = wsf + F_W + W_W1T;
        for (int n = idx; n < 98304; n += stride) {
            int cc = n & 31, C = (n >> 5) & 127, i = n >> 12;
            dst[n] = bw1[(size_t)i * 4096 + cc * 128 + C];
        }
    } else if (task == 7) {
        float* dst = wsf + F_W + W_WSUMT;
        for (int n = idx; n < 98304; n += stride) {
            int C = n & 127, cc = (n >> 7) & 31, i = n >> 12;
            float v = bsw[(size_t)i * 4096 + C * 32 + cc];
            if (i < 23) v += brw[(size_t)i * 4096 + C * 32 + cc];
            dst[n] = v;
        }
    } else {
        float* dst = wsf + F_W + W_BSUM;
        for (int n = idx; n < 3072; n += stride) {
            int i = n >> 7;
            float v = bsb[n];
            if (i < 23) v += brb[n];
            dst[n] = v;
        }
    }
}

// ---------------------------------------------------------------------------
// Zero pad rows of all four bf16 tensors. grid (16, 69, 4).
// ---------------------------------------------------------------------------
__global__ __launch_bounds__(256) void zero_pads_all(
    u16* __restrict__ f0h, u16* __restrict__ f1h,
    u16* __restrict__ yh, u16* __restrict__ d1h)
{
    const int z = blockIdx.z;
    u16* base; int Treal, nb;
    if (z == 0)      { base = f0h; Treal = 1999; nb = 8; }
    else if (z == 1) { base = f1h; Treal = 1997; nb = 8; }
    else if (z == 2) { base = yh;  Treal = 1995; nb = 16; }
    else             { base = d1h; Treal = 1997; nb = 16; }
    if ((int)blockIdx.x >= nb) return;
    const int prcnt = TR - Treal;
    const int pr = blockIdx.y;
    if (pr >= prcnt) return;
    const int row = (pr < RHALO) ? pr : (Treal + pr);
    ((unsigned*)(base + ((size_t)blockIdx.x * TR + row) * 512))[threadIdx.x] = 0u;
}

// ---------------------------------------------------------------------------
// Encoder conv0: 1->512, k16 s8 -> bf16 [t][c]. grid (8, 64, 8)
// ---------------------------------------------------------------------------
__global__ __launch_bounds__(256) void enc0_kernel(
    const float* __restrict__ xr, const float* __restrict__ xi,
    const float* __restrict__ w0, u16* __restrict__ f0h)
{
    const int t  = blockIdx.x * 256 + threadIdx.x;
    const int c0 = blockIdx.y * 8;
    const int b  = blockIdx.z;
    if (t >= 1999) return;
    const float* x = (b < 4) ? (xr + (size_t)b * 16000) : (xi + (size_t)(b - 4) * 16000);
    float xv[16];
    const int base = t * 8;
#pragma unroll
    for (int k = 0; k < 16; k++) xv[k] = x[base + k];
    union { u16 u[8]; uint4 v; } p;
#pragma unroll
    for (int cq = 0; cq < 8; cq++) {
        const float* w = w0 + (size_t)(c0 + cq) * 16;
        float acc = 0.f;
#pragma unroll
        for (int k = 0; k < 16; k++) acc = fmaf(xv[k], w[k], acc);
        p.u[cq] = f2b(acc);
    }
    *(uint4*)&f0h[((size_t)b * TR + RHALO + t) * 512 + c0] = p.v;
}

// ---------------------------------------------------------------------------
// bf16 MFMA conv3 (+PReLU). Tile 128o x 128t, BK=32, j inner. grid (16,4,B)
// OUTF32=0: bf16 [t][c] out via LDS-transpose epilogue (coalesced 256B rows).
// OUTF32=1: fp32 [c][t] out.
// ---------------------------------------------------------------------------
template <int JOFF, int OUTF32>
__global__ __launch_bounds__(256) void conv_mfma(
    const u16* __restrict__ in, u16* __restrict__ out16, float* __restrict__ out32,
    const u16* __restrict__ wM, const float* __restrict__ alpha_p, int Tout)
{
    __shared__ __align__(16) u16 smem[20560];
    u16* As = smem;            // [j][128 o][40]
    u16* Bs = smem + 15360;    // [132 t][40]
    const int tid  = threadIdx.x;
    const int t0   = blockIdx.x * 128;
    const int ob   = blockIdx.y * 128;
    const int b    = blockIdx.z;
    const int l15  = tid & 15;
    const int quad = (tid >> 4) & 3;
    const int wave = tid >> 6;
    const int wm   = (wave & 1) * 64;
    const int wn   = (wave >> 1) * 64;
    const u16* inb = in + (size_t)b * TR * 512;

    f32x4_t acc[4][4];
#pragma unroll
    for (int i = 0; i < 4; i++)
#pragma unroll
        for (int k = 0; k < 4; k++) acc[i][k] = (f32x4_t){0.f, 0.f, 0.f, 0.f};

    for (int c0 = 0; c0 < 512; c0 += 32) {
        for (int v = tid; v < 1536; v += 256) {
            int j = v >> 9, r = (v >> 2) & 127, seg = v & 3;
            *(uint4*)&As[j * 5120 + r * 40 + seg * 8] =
                *(const uint4*)&wM[((size_t)(j * 512 + ob + r)) * 512 + c0 + seg * 8];
        }
        for (int v = tid; v < 520; v += 256) {
            int r = v >> 2, seg = v & 3;
            int row = RHALO + t0 + JOFF + r;
            *(uint4*)&Bs[r * 40 + seg * 8] =
                *(const uint4*)&inb[(size_t)row * 512 + c0 + seg * 8];
        }
        __syncthreads();
#pragma unroll
        for (int j = 0; j < 3; j++) {
            bf16x8_t aw[4], bi[4];
#pragma unroll
            for (int mf = 0; mf < 4; mf++)
                aw[mf] = *(const bf16x8_t*)&As[j * 5120 + (wm + mf * 16 + l15) * 40 + quad * 8];
#pragma unroll
            for (int nf = 0; nf < 4; nf++)
                bi[nf] = *(const bf16x8_t*)&Bs[(wn + nf * 16 + l15 + j) * 40 + quad * 8];
#pragma unroll
            for (int mf = 0; mf < 4; mf++)
#pragma unroll
                for (int nf = 0; nf < 4; nf++) {
                    if (OUTF32)
                        acc[mf][nf] = __builtin_amdgcn_mfma_f32_16x16x32_bf16(
                            bi[nf], aw[mf], acc[mf][nf], 0, 0, 0);
                    else
                        acc[mf][nf] = __builtin_amdgcn_mfma_f32_16x16x32_bf16(
                            aw[mf], bi[nf], acc[mf][nf], 0, 0, 0);
                }
        }
        __syncthreads();
    }

    const float alpha = *alpha_p;
    if (!OUTF32) {
        u16* tile = smem;   // [128 t][136 c]
#pragma unroll
        for (int mf = 0; mf < 4; mf++)
#pragma unroll
            for (int nf = 0; nf < 4; nf++) {
                const int t_loc = wn + nf * 16 + l15;
                const int c_loc = wm + mf * 16 + quad * 4;
                f32x4_t a = acc[mf][nf];
                ushort4 s;
                s.x = f2b(prelu_f(a.x, alpha));
                s.y = f2b(prelu_f(a.y, alpha));
                s.z = f2b(prelu_f(a.z, alpha));
                s.w = f2b(prelu_f(a.w, alpha));
                *(ushort4*)&tile[t_loc * 136 + c_loc] = s;
            }
        __syncthreads();
        for (int v = tid; v < 2048; v += 256) {
            const int row = v >> 4, seg = v & 15;
            const int t = t0 + row;
            if (t < Tout)
                *(uint4*)&out16[((size_t)b * TR + RHALO + t) * 512 + ob + seg * 8] =
                    *(const uint4*)&tile[row * 136 + seg * 8];
        }
    } else {
#pragma unroll
        for (int mf = 0; mf < 4; mf++)
#pragma unroll
            for (int nf = 0; nf < 4; nf++) {
                const int o  = ob + wm + mf * 16 + l15;
                const int tb = t0 + wn + nf * 16 + quad * 4;
                f32x4_t a = acc[mf][nf];
                float v0 = prelu_f(a.x, alpha), v1 = prelu_f(a.y, alpha);
                float v2 = prelu_f(a.z, alpha), v3 = prelu_f(a.w, alpha);
                float* p = out32 + ((size_t)(b * 512 + o)) * ST + HALO + tb;
                if (tb + 3 < Tout) {
                    *(float4*)p = make_float4(v0, v1, v2, v3);
                } else {
                    if (tb + 0 < Tout) p[0] = v0;
                    if (tb + 1 < Tout) p[1] = v1;
                    if (tb + 2 < Tout) p[2] = v2;
                    if (tb + 3 < Tout) p[3] = v3;
                }
            }
    }
}

// ---------------------------------------------------------------------------
// mg_in: o = mg_in_w @ f2 + b (512->128), fused g0 = prelu(pw1_0(o)).
// grid (32, 8)
// ---------------------------------------------------------------------------
__global__ __launch_bounds__(256) void mgin_kernel(
    const float* __restrict__ f2, float* __restrict__ o_buf, float* __restrict__ g_out,
    const float* __restrict__ wT, const float* __restrict__ bias,
    const float* __restrict__ w1T0, const float* __restrict__ b1_0,
    const float* __restrict__ a1_0)
{
    __shared__ float Bs[16][64];
    __shared__ float As[16][128];
    __shared__ float o_lds[128][64];
    const int tid = threadIdx.x;
    const int t0  = blockIdx.x * 64;
    const int b   = blockIdx.y;
    const float* f2b_ = f2 + (size_t)b * 512 * ST + HALO + t0;

    float acc[8][4];
#pragma unroll
    for (int i = 0; i < 8; i++)
#pragma unroll
        for (int k = 0; k < 4; k++) acc[i][k] = 0.f;
    const int tx = tid & 15, ty = tid >> 4;

    for (int c0 = 0; c0 < 512; c0 += 16) {
        {
            int c = tid >> 4, p = tid & 15;
            *(float4*)(&Bs[c][p * 4]) = *(const float4*)(f2b_ + (size_t)(c0 + c) * ST + p * 4);
        }
#pragma unroll
        for (int r = 0; r < 2; r++) {
            int n4 = tid + r * 256;
            int c = n4 >> 5, m4 = n4 & 31;
            *(float4*)(&As[c][m4 * 4]) = *(const float4*)(wT + (size_t)(c0 + c) * 128 + m4 * 4);
        }
        __syncthreads();
#pragma unroll 2
        for (int c = 0; c < 16; c++) {
            float4 bv = *(const float4*)(&Bs[c][tx * 4]);
            float a[8];
            *(float4*)(&a[0]) = *(const float4*)(&As[c][ty * 8]);
            *(float4*)(&a[4]) = *(const float4*)(&As[c][ty * 8 + 4]);
#pragma unroll
            for (int oi = 0; oi < 8; oi++) {
                acc[oi][0] = fmaf(a[oi], bv.x, acc[oi][0]);
                acc[oi][1] = fmaf(a[oi], bv.y, acc[oi][1]);
                acc[oi][2] = fmaf(a[oi], bv.z, acc[oi][2]);
                acc[oi][3] = fmaf(a[oi], bv.w, acc[oi][3]);
            }
        }
        __syncthreads();
    }

    const int tb = t0 + tx * 4;
#pragma unroll
    for (int oi = 0; oi < 8; oi++) {
        const int o = ty * 8 + oi;
        const float bo = bias[o];
        float vv[4];
#pragma unroll
        for (int kk = 0; kk < 4; kk++) vv[kk] = acc[oi][kk] + bo;
        *(float4*)(&o_lds[o][tx * 4]) = make_float4(vv[0], vv[1], vv[2], vv[3]);
        float* orow = o_buf + (size_t)(b * 128 + o) * ST + HALO + tb;
        if (tb + 3 < 1995) {
            *(float4*)orow = make_float4(vv[0], vv[1], vv[2], vv[3]);
        } else {
#pragma unroll
            for (int kk = 0; kk < 4; kk++)
                if (tb + kk < 1995) orow[kk] = vv[kk];
        }
    }
    __syncthreads();

    const int t = tid & 63, cg_ = tid >> 6;
    const float a1 = *a1_0;
    float acc2[8];
#pragma unroll
    for (int q = 0; q < 8; q++) acc2[q] = b1_0[cg_ * 8 + q];
    for (int C = 0; C < 128; C++) {
        const float ov = o_lds[C][t];
        const float4* wr = (const float4*)(w1T0 + (size_t)C * 32 + cg_ * 8);
        float4 w0 = wr[0], w1 = wr[1];
        acc2[0] = fmaf(w0.x, ov, acc2[0]); acc2[1] = fmaf(w0.y, ov, acc2[1]);
        acc2[2] = fmaf(w0.z, ov, acc2[2]); acc2[3] = fmaf(w0.w, ov, acc2[3]);
        acc2[4] = fmaf(w1.x, ov, acc2[4]); acc2[5] = fmaf(w1.y, ov, acc2[5]);
        acc2[6] = fmaf(w1.z, ov, acc2[6]); acc2[7] = fmaf(w1.w, ov, acc2[7]);
    }
    const int tt = t0 + t;
    if (tt < 1995) {
#pragma unroll
        for (int q = 0; q < 8; q++)
            g_out[(size_t)(b * 32 + cg_ * 8 + q) * ST + HALO + tt] = prelu_f(acc2[q], a1);
    }
}

// ---------------------------------------------------------------------------
// Fused TCN: LDS-resident g ping-pong, halo-only global traffic.
// Publish: relaxed flag store after __syncthreads vmcnt drain.
// ---------------------------------------------------------------------------
__device__ __forceinline__ void poll_acquire(const unsigned* flags, int b, int j,
                                             int k, unsigned target)
{
    int lo = j - k; if (lo < 0) lo = 0;
    int hi = j + k; if (hi > 31) hi = 31;
    for (int n = lo; n <= hi; n++) {
        if (n == j) continue;
        const unsigned* p = flags + ((b << 5) + n) * 16;
        while (__hip_atomic_load(p, __ATOMIC_RELAXED, __HIP_MEMORY_SCOPE_AGENT) < target)
            __builtin_amdgcn_s_sleep(2);
    }
    __builtin_amdgcn_fence(__ATOMIC_ACQUIRE, "agent");
}

__device__ __forceinline__ void store_pair_agent(float* dst, int trel, float v0, float v1)
{
    if (trel + 1 < 1995) {
        unsigned long long raw =
            ((unsigned long long)__float_as_uint(v1) << 32) | __float_as_uint(v0);
        __hip_atomic_store((unsigned long long*)dst, raw,
                           __ATOMIC_RELAXED, __HIP_MEMORY_SCOPE_AGENT);
    } else if (trel < 1995) {
        __hip_atomic_store(dst, v0, __ATOMIC_RELAXED, __HIP_MEMORY_SCOPE_AGENT);
    }
}

__global__ __launch_bounds__(512) void tcn_fused(
    float* __restrict__ g0, float* __restrict__ g1,
    float* __restrict__ g2, float* __restrict__ g3,
    float* __restrict__ o_buf,
    const float* __restrict__ dw_all, const float* __restrict__ db_all,
    const float* __restrict__ a2_all,
    const float* __restrict__ wsumT_all, const float* __restrict__ bsum_all,
    const float* __restrict__ w1T_all, const float* __restrict__ b1_all,
    const float* __restrict__ a1_all, unsigned* __restrict__ wflag)
{
    __shared__ __align__(16) float w_lds[8192];
    __shared__ __align__(16) float h_lds[32 * 68];
    __shared__ __align__(16) float o_lds[128 * 68];
    __shared__ __align__(16) float g_lds[2][32 * 68];
    __shared__ __align__(16) float halo_lds[32 * 260];
    const int tid = threadIdx.x;
    const int blk = blockIdx.x;
    const int b   = blk & 7;
    const int jt  = blk >> 3;
    const int t0  = jt * 64;
    float* gb[4] = { g0, g1, g2, g3 };

#pragma unroll
    for (int k = 0; k < 4; k++) {
        int n = tid + k * 512;
        int C = n >> 4, seg = n & 15;
        *(float4*)&o_lds[C * 68 + seg * 4] =
            *(const float4*)&o_buf[((size_t)(b * 128 + C)) * ST + HALO + t0 + seg * 4];
    }
    {
        int cc = tid >> 4, seg = tid & 15;
        *(float4*)&g_lds[0][cc * 68 + seg * 4] =
            *(const float4*)&g0[((size_t)(b * 32 + cc)) * ST + HALO + t0 + seg * 4];
    }

    for (int i = 0; i < 24; i++) {
        const int dil  = 1 << (i & 7);
        const int dil2 = (dil < 2) ? 2 : dil;
        const int k_rd = (dil > 64) ? 2 : 1;
        const float* gin_g = gb[i & 3];
        float* gout_g      = gb[(i + 1) & 3];
        float* gin_lds  = g_lds[i & 1];
        float* gout_lds = g_lds[(i + 1) & 1];

        {
            const float* wsum = wsumT_all + (size_t)i * 4096;
#pragma unroll
            for (int k = 0; k < 2; k++) {
                int n = tid + k * 512;
                *(float4*)&w_lds[n * 4] = *(const float4*)&wsum[n * 4];
            }
            if (i < 23) {
                const float* w1 = w1T_all + (size_t)(i + 1) * 4096;
#pragma unroll
                for (int k = 0; k < 2; k++) {
                    int n = tid + k * 512;
                    *(float4*)&w_lds[4096 + n * 4] = *(const float4*)&w1[n * 4];
                }
            }
        }

        if (i > 0 && tid == 0) poll_acquire(wflag, b, jt, k_rd, (unsigned)i);
        __syncthreads();

        // halo load: dsh covers dil2 up to 128 (7 bits) — r13 fix.
        {
            const int dsh = (dil2 >= 128) ? 7 : (dil2 >= 64) ? 6 : (dil2 >= 32) ? 5
                          : (dil2 >= 16) ? 4 : (dil2 >= 8) ? 3 : (dil2 >= 4) ? 2 : 1;
            const int total = 32 << dsh;
            for (int n = tid; n < total; n += 512) {
                const int cc = n >> dsh;
                const int pi = n & (dil2 - 1);
                const int hc = pi * 2;
                const int tg = (hc < dil2) ? (t0 - dil2 + hc) : (t0 + 64 + hc - dil2);
                float v0 = 0.f, v1 = 0.f;
                const float* src = gin_g + ((size_t)(b * 32 + cc)) * ST + HALO + tg;
                if (tg >= 0 && tg + 1 < 1995) {
                    unsigned long long raw = __hip_atomic_load(
                        (const unsigned long long*)src,
                        __ATOMIC_RELAXED, __HIP_MEMORY_SCOPE_AGENT);
                    v0 = __uint_as_float((unsigned)raw);
                    v1 = __uint_as_float((unsigned)(raw >> 32));
                } else {
                    if (tg >= 0 && tg < 1995)
                        v0 = __hip_atomic_load(src, __ATOMIC_RELAXED,
                                               __HIP_MEMORY_SCOPE_AGENT);
                    if (tg + 1 >= 0 && tg + 1 < 1995)
                        v1 = __hip_atomic_load(src + 1, __ATOMIC_RELAXED,
                                               __HIP_MEMORY_SCOPE_AGENT);
                }
                halo_lds[cc * 260 + hc]     = v0;
                halo_lds[cc * 260 + hc + 1] = v1;
            }
        }
        __syncthreads();

        {
            const float a2 = a2_all[i];
            const int t = tid & 63, cc0 = (tid >> 6) * 4;
            const int tt = t0 + t;
#pragma unroll
            for (int q = 0; q < 4; q++) {
                const int cc = cc0 + q;
                const float w0 = dw_all[i * 96 + cc * 3 + 0];
                const float w1v = dw_all[i * 96 + cc * 3 + 1];
                const float w2 = dw_all[i * 96 + cc * 3 + 2];
                const float ctr = gin_lds[cc * 68 + t];
                float lo = 0.f, hi = 0.f;
                const int tm = tt - dil;
                if (tm >= 0)
                    lo = (tm >= t0) ? gin_lds[cc * 68 + (tm - t0)]
                                    : halo_lds[cc * 260 + (tm - t0 + dil2)];
                const int tp = tt + dil;
                if (tp < 1995)
                    hi = (tp < t0 + 64) ? gin_lds[cc * 68 + (tp - t0)]
                                        : halo_lds[cc * 260 + (dil2 + tp - t0 - 64)];
                float s = db_all[i * 32 + cc] + w1v * ctr;
                s = fmaf(w0, lo, s);
                s = fmaf(w2, hi, s);
                h_lds[cc * 68 + t] = prelu_f(s, a2);
            }
        }
        __syncthreads();

        {
            const int c4 = tid & 31, t4 = tid >> 5;
            float s[4][4];
#pragma unroll
            for (int ci = 0; ci < 4; ci++)
#pragma unroll
                for (int tj = 0; tj < 4; tj++) s[ci][tj] = 0.f;
            for (int cc = 0; cc < 32; cc++) {
                float4 w4 = *(const float4*)&w_lds[cc * 128 + c4 * 4];
                float4 h4 = *(const float4*)&h_lds[cc * 68 + t4 * 4];
                const float wv[4] = {w4.x, w4.y, w4.z, w4.w};
                const float hv[4] = {h4.x, h4.y, h4.z, h4.w};
#pragma unroll
                for (int ci = 0; ci < 4; ci++)
#pragma unroll
                    for (int tj = 0; tj < 4; tj++)
                        s[ci][tj] = fmaf(wv[ci], hv[tj], s[ci][tj]);
            }
#pragma unroll
            for (int ci = 0; ci < 4; ci++) {
                const int C = c4 * 4 + ci;
                const float bs = bsum_all[i * 128 + C];
                float4 ov = *(float4*)&o_lds[C * 68 + t4 * 4];
                ov.x += s[ci][0] + bs;
                ov.y += s[ci][1] + bs;
                ov.z += s[ci][2] + bs;
                ov.w += s[ci][3] + bs;
                *(float4*)&o_lds[C * 68 + t4 * 4] = ov;
            }
        }

        if (i == 23) break;
        __syncthreads();

        {
            const int cc = tid & 31, tq = tid >> 5;
            const float a1 = a1_all[i + 1];
            const float b1v = b1_all[(i + 1) * 32 + cc];
            float acc2[4] = {b1v, b1v, b1v, b1v};
            for (int C = 0; C < 128; C++) {
                const float wv = w_lds[4096 + C * 32 + cc];
                float4 o4 = *(const float4*)&o_lds[C * 68 + tq * 4];
                acc2[0] = fmaf(wv, o4.x, acc2[0]);
                acc2[1] = fmaf(wv, o4.y, acc2[1]);
                acc2[2] = fmaf(wv, o4.z, acc2[2]);
                acc2[3] = fmaf(wv, o4.w, acc2[3]);
            }
#pragma unroll
            for (int kk = 0; kk < 4; kk++)
                gout_lds[cc * 68 + tq * 4 + kk] = prelu_f(acc2[kk], a1);
        }
        __syncthreads();

        {
            const int dnext = 1 << ((i + 1) & 7);
            int md2 = (dnext > 64) ? 64 : dnext;
            if (md2 < 2) md2 = 2;
            if (md2 >= 64) {
                for (int n = tid; n < 1024; n += 512) {
                    const int cc = n >> 5, pi = n & 31;
                    const int lt = pi * 2;
                    float* dst = gout_g + ((size_t)(b * 32 + cc)) * ST + HALO + t0 + lt;
                    store_pair_agent(dst, t0 + lt,
                                     gout_lds[cc * 68 + lt], gout_lds[cc * 68 + lt + 1]);
                }
            } else {
                const int msh = (md2 >= 32) ? 5 : (md2 >= 16) ? 4 : (md2 >= 8) ? 3
                              : (md2 >= 4) ? 2 : 1;
                const int total = 32 << msh;
                for (int n = tid; n < total; n += 512) {
                    const int cc = n >> msh;
                    const int pi = n & (md2 - 1);
                    const int hc = pi * 2;
                    const int lt = (hc < md2) ? hc : (64 - 2 * md2 + hc);
                    float* dst = gout_g + ((size_t)(b * 32 + cc)) * ST + HALO + t0 + lt;
                    store_pair_agent(dst, t0 + lt,
                                     gout_lds[cc * 68 + lt], gout_lds[cc * 68 + lt + 1]);
                }
            }
        }
        __syncthreads();   // vmcnt drain: write-through stores acked at coherence point

        if (tid == 0)
            __hip_atomic_store(&wflag[((b << 5) + jt) * 16], (unsigned)(i + 1),
                               __ATOMIC_RELAXED, __HIP_MEMORY_SCOPE_AGENT);
    }

    __syncthreads();
#pragma unroll
    for (int k = 0; k < 4; k++) {
        int n = tid + k * 512;
        int C = n >> 4, seg = n & 15;
        *(float4*)&o_buf[((size_t)(b * 128 + C)) * ST + HALO + t0 + seg * 4] =
            *(const float4*)&o_lds[C * 68 + seg * 4];
    }
}

// ---------------------------------------------------------------------------
// mask + multiply -> y bf16 [t][c] via LDS transpose. grid (32, 4, 8)
// ---------------------------------------------------------------------------
__global__ __launch_bounds__(256) void mask_kernel(
    const float* __restrict__ o_buf, const float* __restrict__ f2, u16* __restrict__ yh,
    const float* __restrict__ wT, const float* __restrict__ mb,
    const float* __restrict__ a_out_p)
{
    __shared__ __align__(16) char smem[65536];
    float (*o_lds)[64]  = (float (*)[64])smem;
    float (*w_lds)[256] = (float (*)[256])(smem + 32768);
    u16* tile = (u16*)smem;

    const int tid = threadIdx.x;
    const int t0  = blockIdx.x * 64;
    const int m0  = blockIdx.y * 256;
    const int b   = blockIdx.z;
    const float ao = *a_out_p;

#pragma unroll
    for (int r = 0; r < 8; r++) {
        int n4 = tid + r * 256;
        int C = n4 >> 4, p = n4 & 15;
        float4 v = *(const float4*)(o_buf + (size_t)(b * 128 + C) * ST + HALO + t0 + p * 4);
        v.x = prelu_f(v.x, ao); v.y = prelu_f(v.y, ao);
        v.z = prelu_f(v.z, ao); v.w = prelu_f(v.w, ao);
        *(float4*)(&o_lds[C][p * 4]) = v;
    }

    float acc[16][4];
#pragma unroll
    for (int i = 0; i < 16; i++)
#pragma unroll
        for (int k = 0; k < 4; k++) acc[i][k] = 0.f;
    const int tx = tid & 15, my = tid >> 4;

    for (int C0 = 0; C0 < 128; C0 += 32) {
#pragma unroll
        for (int r = 0; r < 8; r++) {
            int n4 = tid + r * 256;
            int c = n4 >> 6, m4 = n4 & 63;
            *(float4*)(&w_lds[c][m4 * 4]) =
                *(const float4*)(wT + (size_t)(C0 + c) * 1024 + m0 + m4 * 4);
        }
        __syncthreads();
#pragma unroll 2
        for (int c = 0; c < 32; c++) {
            float4 bv = *(const float4*)(&o_lds[C0 + c][tx * 4]);
            float a[16];
            *(float4*)(&a[0])  = *(const float4*)(&w_lds[c][my * 16 + 0]);
            *(float4*)(&a[4])  = *(const float4*)(&w_lds[c][my * 16 + 4]);
            *(float4*)(&a[8])  = *(const float4*)(&w_lds[c][my * 16 + 8]);
            *(float4*)(&a[12]) = *(const float4*)(&w_lds[c][my * 16 + 12]);
#pragma unroll
            for (int mm = 0; mm < 16; mm++) {
                acc[mm][0] = fmaf(a[mm], bv.x, acc[mm][0]);
                acc[mm][1] = fmaf(a[mm], bv.y, acc[mm][1]);
                acc[mm][2] = fmaf(a[mm], bv.z, acc[mm][2]);
                acc[mm][3] = fmaf(a[mm], bv.w, acc[mm][3]);
            }
        }
        __syncthreads();
    }

    const int tb = t0 + tx * 4;
#pragma unroll
    for (int mm = 0; mm < 16; mm++) {
        const int mi = m0 + my * 16 + mm;
        const float bb = mb[mi];
        const int F = mi & 511;
        const float* f2row = f2 + (size_t)(b * 512 + F) * ST + HALO + tb;
#pragma unroll
        for (int kk = 0; kk < 4; kk++) {
            const float mval = 1.f / (1.f + __expf(-(acc[mm][kk] + bb)));
            acc[mm][kk] = mval * f2row[kk];
        }
    }
#pragma unroll
    for (int kk = 0; kk < 4; kk++) {
        const int row = tx * 4 + kk;
#pragma unroll
        for (int half = 0; half < 2; half++) {
            union { u16 u[8]; uint4 v; } p;
#pragma unroll
            for (int q = 0; q < 8; q++) p.u[q] = f2b(acc[half * 8 + q][kk]);
            *(uint4*)&tile[row * 280 + my * 16 + half * 8] = p.v;
        }
    }
    __syncthreads();
    const int F0 = m0 & 511, sIdx = m0 >> 9;
    u16* ybase = yh + ((size_t)(b * 2 + sIdx) * TR) * 512;
    for (int i = tid; i < 2048; i += 256) {
        const int row = i >> 5, seg = i & 31;
        const int t = t0 + row;
        if (t < 1995)
            *(uint4*)&ybase[(size_t)(RHALO + t) * 512 + F0 + seg * 8] =
                *(const uint4*)&tile[row * 280 + seg * 8];
    }
}

// ---------------------------------------------------------------------------
// Decoder tconv3: 512->1, k16 s8. OOB taps read as 0. grid (63, 16)
// ---------------------------------------------------------------------------
__global__ __launch_bounds__(256) void dec3_kernel(
    const float* __restrict__ d2, const float* __restrict__ w3, float* __restrict__ out)
{
    __shared__ float tile[512][34];
    const int tid = threadIdx.x;
    const int bb  = blockIdx.y;
    const int tau0 = blockIdx.x * 256;
    const int tbase = (tau0 >> 3) - 1;
    const float* src = d2 + (size_t)bb * 512 * ST + HALO + tbase;
    for (int n = tid; n < 512 * 34; n += 256) {
        int o = n / 34, i = n % 34;
        const int tg = tbase + i;
        tile[o][i] = (tg >= 0 && tg < 1999) ? src[(size_t)o * ST + i] : 0.f;
    }
    __syncthreads();

    const int tau = tau0 + tid;
    if (tau >= 16000) return;
    const int k1 = tau & 7;
    const int t1l = (tid >> 3) + 1;
    float acc = 0.f;
#pragma unroll 8
    for (int o = 0; o < 512; o++) {
        acc = fmaf(tile[o][t1l],     w3[o * 16 + k1],     acc);
        acc = fmaf(tile[o][t1l - 1], w3[o * 16 + 8 + k1], acc);
    }
    const int p = bb >> 1, s = bb & 1;
    out[(size_t)(p * 2 + s) * 16000 + tau] = acc;
}

// ---------------------------------------------------------------------------
extern "C" void kernel_launch(void* const* d_in, const int* in_sizes, int n_in,
                              void* d_out, int out_size, void* d_ws, size_t ws_size,
                              hipStream_t stream)
{
    (void)in_sizes; (void)n_in; (void)out_size; (void)ws_size;
    float* ws  = (float*)d_ws;
    u16*   wsu = (u16*)d_ws;
    const float* x_real   = (const float*)d_in[0];
    const float* x_imag   = (const float*)d_in[1];
    const float* enc_w0   = (const float*)d_in[2];
    const float* enc_w1   = (const float*)d_in[3];
    const float* enc_w2   = (const float*)d_in[4];
    const float* enc_a    = (const float*)d_in[5];
    const float* mg_in_w  = (const float*)d_in[6];
    const float* mg_in_b  = (const float*)d_in[7];
    const float* blk_w1   = (const float*)d_in[8];
    const float* blk_b1   = (const float*)d_in[9];
    const float* blk_a1   = (const float*)d_in[10];
    const float* blk_dw   = (const float*)d_in[11];
    const float* blk_db   = (const float*)d_in[12];
    const float* blk_a2   = (const float*)d_in[13];
    const float* blk_rw   = (const float*)d_in[14];
    const float* blk_rb   = (const float*)d_in[15];
    const float* blk_sw   = (const float*)d_in[16];
    const float* blk_sb   = (const float*)d_in[17];
    const float* mg_out_a = (const float*)d_in[18];
    const float* mg_out_w = (const float*)d_in[19];
    const float* mg_out_b = (const float*)d_in[20];
    const float* dec_w1   = (const float*)d_in[21];
    const float* dec_w2   = (const float*)d_in[22];
    const float* dec_a    = (const float*)d_in[23];
    const float* dec_w3   = (const float*)d_in[24];
    float* out = (float*)d_out;

    u16*   f0h   = wsu + U_F0H;
    u16*   f1h   = wsu + U_F1H;
    float* f2    = ws  + F_F2;
    float* d2    = ws  + F_D2;
    u16*   yh    = wsu + U_YH;
    u16*   d1h   = wsu + U_D1H;
    float* obuf  = ws  + F_O;
    float* g0    = ws  + F_G0;
    float* g1    = ws  + F_G1;
    float* g2    = ws  + F_G2;
    float* g3    = ws  + F_G3;
    float* WF    = ws  + F_W;
    u16*   WB    = wsu + U_WB;
    unsigned* flags = (unsigned*)(ws + F_FLAG);

    const dim3 blk(256);

    prep_weights<<<dim3(64, 9), blk, 0, stream>>>(enc_w1, enc_w2, dec_w1, dec_w2,
        mg_in_w, mg_out_w, blk_w1, blk_rw, blk_rb, blk_sw, blk_sb, ws, wsu);

    zero_pads_all<<<dim3(16, 69, 4), blk, 0, stream>>>(f0h, f1h, yh, d1h);

    (void)hipMemsetAsync(flags, 0, 4096 * sizeof(unsigned), stream);

    enc0_kernel<<<dim3(8, 64, 8), blk, 0, stream>>>(x_real, x_imag, enc_w0, f0h);

    conv_mfma<0, 0><<<dim3(16, 4, 8), blk, 0, stream>>>(
        f0h, f1h, nullptr, WB + 0 * 786432, enc_a + 0, 1997);
    conv_mfma<0, 1><<<dim3(16, 4, 8), blk, 0, stream>>>(
        f1h, nullptr, f2, WB + 1 * 786432, enc_a + 1, 1995);

    mgin_kernel<<<dim3(32, 8), blk, 0, stream>>>(f2, obuf, g0, WF + W_MGIN, mg_in_b,
        WF + W_W1T, blk_b1, blk_a1);

    {
        const float* dwp   = blk_dw;
        const float* dbp   = blk_db;
        const float* a2p   = blk_a2;
        const float* wsump = WF + W_WSUMT;
        const float* bsump = WF + W_BSUM;
        const float* w1p   = WF + W_W1T;
        const float* b1p   = blk_b1;
        const float* a1p   = blk_a1;
        unsigned* flg = flags;
        void* args[] = { &g0, &g1, &g2, &g3, &obuf,
                         (void*)&dwp, (void*)&dbp, (void*)&a2p,
                         (void*)&wsump, (void*)&bsump, (void*)&w1p,
                         (void*)&b1p, (void*)&a1p, &flg };
        (void)hipLaunchCooperativeKernel((void*)tcn_fused, dim3(256), dim3(512),
                                         args, 0, stream);
    }

    mask_kernel<<<dim3(32, 4, 8), blk, 0, stream>>>(obuf, f2, yh,
        WF + W_MGOUT, mg_out_b, mg_out_a);

    conv_mfma<-2, 0><<<dim3(16, 4, 16), blk, 0, stream>>>(
        yh, d1h, nullptr, WB + 2 * 786432, dec_a + 0, 1997);
    conv_mfma<-2, 1><<<dim3(16, 4, 16), blk, 0, stream>>>(
        d1h, nullptr, d2, WB + 3 * 786432, dec_a + 1, 1999);

    dec3_kernel<<<dim3(63, 16), blk, 0, stream>>>(d2, dec_w3, out);
}

// Round 17
// 951.300 us; speedup vs baseline: 1.2090x; 1.0007x over previous
//
#include <hip/hip_runtime.h>
#include <hip/hip_cooperative_groups.h>

namespace cg = cooperative_groups;

// ---------------------------------------------------------------------------
// DualRealConvTasNet — round 17: round 16 + prologue consolidation:
// prep_weights + zero_pads_all + flags-memset merged into one prep_all
// kernel (3 dispatches -> 1). Everything else identical to the verified
// 951.9 µs / absmax 0.009765625 state.
// ---------------------------------------------------------------------------

typedef unsigned short u16;
typedef __attribute__((ext_vector_type(8))) short bf16x8_t;
typedef __attribute__((ext_vector_type(4))) float f32x4_t;

#define ST    2064
#define HALO  8
#define TR    2064
#define RHALO 8

// ---- workspace layout ----
#define U_F0H   0ULL
#define U_F1H   8454144ULL
#define F_F2    8454144ULL
#define F_D2    0ULL
#define U_YH    33816576ULL
#define U_D1H   50724864ULL
#define F_O     33816576ULL
#define F_G0    35930112ULL
#define F_G1    36458496ULL
#define F_W     36986880ULL
#define W_MGIN  0ULL
#define W_MGOUT 65536ULL
#define W_W1T   196608ULL
#define W_WSUMT 294912ULL
#define W_BSUM  393216ULL
#define U_WB    74766336ULL
#define F_FLAG  38956032ULL
#define F_G2    38964224ULL
#define F_G3    39492608ULL

__device__ __forceinline__ float prelu_f(float x, float a) { return x >= 0.f ? x : a * x; }
__device__ __forceinline__ u16 f2b(float f) {
    unsigned u = __float_as_uint(f);
    return (u16)((u + 0x7FFF + ((u >> 16) & 1)) >> 16);
}

// ---------------------------------------------------------------------------
// Prologue: weight prep (tasks 0-8), pad zeroing (task 9), flag zeroing
// (task 10). grid (64, 11) x 256.
// ---------------------------------------------------------------------------
__global__ __launch_bounds__(256) void prep_all(
    const float* __restrict__ ew1, const float* __restrict__ ew2,
    const float* __restrict__ dw1, const float* __restrict__ dw2,
    const float* __restrict__ mgin_w, const float* __restrict__ mgout_w,
    const float* __restrict__ bw1, const float* __restrict__ brw,
    const float* __restrict__ brb, const float* __restrict__ bsw,
    const float* __restrict__ bsb, float* __restrict__ wsf, u16* __restrict__ wsb,
    unsigned* __restrict__ flags)
{
    const int task = blockIdx.y;
    const int idx  = blockIdx.x * 256 + threadIdx.x;
    const int stride = gridDim.x * 256;
    if (task < 4) {
        const float* src = (task == 0) ? ew1 : (task == 1) ? ew2 : (task == 2) ? dw1 : dw2;
        u16* dst = wsb + U_WB + (size_t)task * 786432ULL;
        const bool dec = (task >= 2);
        for (int n = idx; n < 786432; n += stride) {
            int j = n >> 18, o = (n >> 9) & 511, c = n & 511;
            float v = dec ? src[(size_t)c * 1536 + o * 3 + (2 - j)]
                          : src[(size_t)o * 1536 + c * 3 + j];
            dst[n] = f2b(v);
        }
    } else if (task == 4) {
        float* dst = wsf + F_W + W_MGIN;
        for (int n = idx; n < 65536; n += stride) {
            int o = n & 127, c = n >> 7;
            dst[n] = mgin_w[(size_t)o * 512 + c];
        }
    } else if (task == 5) {
        float* dst = wsf + F_W + W_MGOUT;
        for (int n = idx; n < 131072; n += stride) {
            int m = n & 1023, c = n >> 10;
            dst[n] = mgout_w[(size_t)m * 128 + c];
        }
    } else if (task == 6) {
        float* dst = wsf + F_W + W_W1T;
        for (int n = idx; n < 98304; n += stride) {
            int cc = n & 31, C = (n >> 5) & 127, i = n >> 12;
            dst[n] = bw1[(size_t)i * 4096 + cc * 128 + C];
        }
    } else if (task == 7) {
        float* dst = wsf + F_W + W_WSUMT;
        for (int n = idx; n < 98304; n += stride) {
            int C = n & 127, cc = (n >> 7) & 31, i = n >> 12;
            float v = bsw[(size_t)i * 4096 + C * 32 + cc];
            if (i < 23) v += brw[(size_t)i * 4096 + C * 32 + cc];
            dst[n] = v;
        }
    } else if (task == 8) {
        float* dst = wsf + F_W + W_BSUM;
        for (int n = idx; n < 3072; n += stride) {
            int i = n >> 7;
            float v = bsb[n];
            if (i < 23) v += brb[n];
            dst[n] = v;
        }
    } else if (task == 9) {
        // zero pad rows of the four bf16 tensors (uint granularity, 256/row)
        const unsigned long long uoff[4] = { U_F0H, U_F1H, U_YH, U_D1H };
        const int nbArr[4]   = { 8, 8, 16, 16 };
        const int trArr[4]   = { 1999, 1997, 1995, 1997 };
#pragma unroll
        for (int z = 0; z < 4; z++) {
            unsigned* base = (unsigned*)(wsb + uoff[z]);
            const int nb = nbArr[z], Treal = trArr[z];
            const int prcnt = TR - Treal;
            const int total = nb * prcnt * 256;      // uints
            for (int n = idx; n < total; n += stride) {
                const int col = n & 255;
                const int r   = n >> 8;
                const int bb  = r / prcnt;
                const int pr  = r % prcnt;
                const int row = (pr < RHALO) ? pr : (Treal + pr);
                base[((size_t)bb * TR + row) * 256 + col] = 0u;
            }
        }
    } else {
        for (int n = idx; n < 4096; n += stride) flags[n] = 0u;
    }
}

// ---------------------------------------------------------------------------
// Encoder conv0: 1->512, k16 s8 -> bf16 [t][c]. grid (8, 64, 8)
// ---------------------------------------------------------------------------
__global__ __launch_bounds__(256) void enc0_kernel(
    const float* __restrict__ xr, const float* __restrict__ xi,
    const float* __restrict__ w0, u16* __restrict__ f0h)
{
    const int t  = blockIdx.x * 256 + threadIdx.x;
    const int c0 = blockIdx.y * 8;
    const int b  = blockIdx.z;
    if (t >= 1999) return;
    const float* x = (b < 4) ? (xr + (size_t)b * 16000) : (xi + (size_t)(b - 4) * 16000);
    float xv[16];
    const int base = t * 8;
#pragma unroll
    for (int k = 0; k < 16; k++) xv[k] = x[base + k];
    union { u16 u[8]; uint4 v; } p;
#pragma unroll
    for (int cq = 0; cq < 8; cq++) {
        const float* w = w0 + (size_t)(c0 + cq) * 16;
        float acc = 0.f;
#pragma unroll
        for (int k = 0; k < 16; k++) acc = fmaf(xv[k], w[k], acc);
        p.u[cq] = f2b(acc);
    }
    *(uint4*)&f0h[((size_t)b * TR + RHALO + t) * 512 + c0] = p.v;
}

// ---------------------------------------------------------------------------
// bf16 MFMA conv3 (+PReLU). Tile 128o x 128t, BK=32, j inner. grid (16,4,B)
// OUTF32=0: bf16 [t][c] out via LDS-transpose epilogue.
// OUTF32=1: fp32 [c][t] out.
// ---------------------------------------------------------------------------
template <int JOFF, int OUTF32>
__global__ __launch_bounds__(256) void conv_mfma(
    const u16* __restrict__ in, u16* __restrict__ out16, float* __restrict__ out32,
    const u16* __restrict__ wM, const float* __restrict__ alpha_p, int Tout)
{
    __shared__ __align__(16) u16 smem[20560];
    u16* As = smem;            // [j][128 o][40]
    u16* Bs = smem + 15360;    // [132 t][40]
    const int tid  = threadIdx.x;
    const int t0   = blockIdx.x * 128;
    const int ob   = blockIdx.y * 128;
    const int b    = blockIdx.z;
    const int l15  = tid & 15;
    const int quad = (tid >> 4) & 3;
    const int wave = tid >> 6;
    const int wm   = (wave & 1) * 64;
    const int wn   = (wave >> 1) * 64;
    const u16* inb = in + (size_t)b * TR * 512;

    f32x4_t acc[4][4];
#pragma unroll
    for (int i = 0; i < 4; i++)
#pragma unroll
        for (int k = 0; k < 4; k++) acc[i][k] = (f32x4_t){0.f, 0.f, 0.f, 0.f};

    for (int c0 = 0; c0 < 512; c0 += 32) {
        for (int v = tid; v < 1536; v += 256) {
            int j = v >> 9, r = (v >> 2) & 127, seg = v & 3;
            *(uint4*)&As[j * 5120 + r * 40 + seg * 8] =
                *(const uint4*)&wM[((size_t)(j * 512 + ob + r)) * 512 + c0 + seg * 8];
        }
        for (int v = tid; v < 520; v += 256) {
            int r = v >> 2, seg = v & 3;
            int row = RHALO + t0 + JOFF + r;
            *(uint4*)&Bs[r * 40 + seg * 8] =
                *(const uint4*)&inb[(size_t)row * 512 + c0 + seg * 8];
        }
        __syncthreads();
#pragma unroll
        for (int j = 0; j < 3; j++) {
            bf16x8_t aw[4], bi[4];
#pragma unroll
            for (int mf = 0; mf < 4; mf++)
                aw[mf] = *(const bf16x8_t*)&As[j * 5120 + (wm + mf * 16 + l15) * 40 + quad * 8];
#pragma unroll
            for (int nf = 0; nf < 4; nf++)
                bi[nf] = *(const bf16x8_t*)&Bs[(wn + nf * 16 + l15 + j) * 40 + quad * 8];
#pragma unroll
            for (int mf = 0; mf < 4; mf++)
#pragma unroll
                for (int nf = 0; nf < 4; nf++) {
                    if (OUTF32)
                        acc[mf][nf] = __builtin_amdgcn_mfma_f32_16x16x32_bf16(
                            bi[nf], aw[mf], acc[mf][nf], 0, 0, 0);
                    else
                        acc[mf][nf] = __builtin_amdgcn_mfma_f32_16x16x32_bf16(
                            aw[mf], bi[nf], acc[mf][nf], 0, 0, 0);
                }
        }
        __syncthreads();
    }

    const float alpha = *alpha_p;
    if (!OUTF32) {
        u16* tile = smem;   // [128 t][136 c]
#pragma unroll
        for (int mf = 0; mf < 4; mf++)
#pragma unroll
            for (int nf = 0; nf < 4; nf++) {
                const int t_loc = wn + nf * 16 + l15;
                const int c_loc = wm + mf * 16 + quad * 4;
                f32x4_t a = acc[mf][nf];
                ushort4 s;
                s.x = f2b(prelu_f(a.x, alpha));
                s.y = f2b(prelu_f(a.y, alpha));
                s.z = f2b(prelu_f(a.z, alpha));
                s.w = f2b(prelu_f(a.w, alpha));
                *(ushort4*)&tile[t_loc * 136 + c_loc] = s;
            }
        __syncthreads();
        for (int v = tid; v < 2048; v += 256) {
            const int row = v >> 4, seg = v & 15;
            const int t = t0 + row;
            if (t < Tout)
                *(uint4*)&out16[((size_t)b * TR + RHALO + t) * 512 + ob + seg * 8] =
                    *(const uint4*)&tile[row * 136 + seg * 8];
        }
    } else {
#pragma unroll
        for (int mf = 0; mf < 4; mf++)
#pragma unroll
            for (int nf = 0; nf < 4; nf++) {
                const int o  = ob + wm + mf * 16 + l15;
                const int tb = t0 + wn + nf * 16 + quad * 4;
                f32x4_t a = acc[mf][nf];
                float v0 = prelu_f(a.x, alpha), v1 = prelu_f(a.y, alpha);
                float v2 = prelu_f(a.z, alpha), v3 = prelu_f(a.w, alpha);
                float* p = out32 + ((size_t)(b * 512 + o)) * ST + HALO + tb;
                if (tb + 3 < Tout) {
                    *(float4*)p = make_float4(v0, v1, v2, v3);
                } else {
                    if (tb + 0 < Tout) p[0] = v0;
                    if (tb + 1 < Tout) p[1] = v1;
                    if (tb + 2 < Tout) p[2] = v2;
                    if (tb + 3 < Tout) p[3] = v3;
                }
            }
    }
}

// ---------------------------------------------------------------------------
// mg_in: o = mg_in_w @ f2 + b (512->128), fused g0 = prelu(pw1_0(o)).
// grid (32, 8)
// ---------------------------------------------------------------------------
__global__ __launch_bounds__(256) void mgin_kernel(
    const float* __restrict__ f2, float* __restrict__ o_buf, float* __restrict__ g_out,
    const float* __restrict__ wT, const float* __restrict__ bias,
    const float* __restrict__ w1T0, const float* __restrict__ b1_0,
    const float* __restrict__ a1_0)
{
    __shared__ float Bs[16][64];
    __shared__ float As[16][128];
    __shared__ float o_lds[128][64];
    const int tid = threadIdx.x;
    const int t0  = blockIdx.x * 64;
    const int b   = blockIdx.y;
    const float* f2b_ = f2 + (size_t)b * 512 * ST + HALO + t0;

    float acc[8][4];
#pragma unroll
    for (int i = 0; i < 8; i++)
#pragma unroll
        for (int k = 0; k < 4; k++) acc[i][k] = 0.f;
    const int tx = tid & 15, ty = tid >> 4;

    for (int c0 = 0; c0 < 512; c0 += 16) {
        {
            int c = tid >> 4, p = tid & 15;
            *(float4*)(&Bs[c][p * 4]) = *(const float4*)(f2b_ + (size_t)(c0 + c) * ST + p * 4);
        }
#pragma unroll
        for (int r = 0; r < 2; r++) {
            int n4 = tid + r * 256;
            int c = n4 >> 5, m4 = n4 & 31;
            *(float4*)(&As[c][m4 * 4]) = *(const float4*)(wT + (size_t)(c0 + c) * 128 + m4 * 4);
        }
        __syncthreads();
#pragma unroll 2
        for (int c = 0; c < 16; c++) {
            float4 bv = *(const float4*)(&Bs[c][tx * 4]);
            float a[8];
            *(float4*)(&a[0]) = *(const float4*)(&As[c][ty * 8]);
            *(float4*)(&a[4]) = *(const float4*)(&As[c][ty * 8 + 4]);
#pragma unroll
            for (int oi = 0; oi < 8; oi++) {
                acc[oi][0] = fmaf(a[oi], bv.x, acc[oi][0]);
                acc[oi][1] = fmaf(a[oi], bv.y, acc[oi][1]);
                acc[oi][2] = fmaf(a[oi], bv.z, acc[oi][2]);
                acc[oi][3] = fmaf(a[oi], bv.w, acc[oi][3]);
            }
        }
        __syncthreads();
    }

    const int tb = t0 + tx * 4;
#pragma unroll
    for (int oi = 0; oi < 8; oi++) {
        const int o = ty * 8 + oi;
        const float bo = bias[o];
        float vv[4];
#pragma unroll
        for (int kk = 0; kk < 4; kk++) vv[kk] = acc[oi][kk] + bo;
        *(float4*)(&o_lds[o][tx * 4]) = make_float4(vv[0], vv[1], vv[2], vv[3]);
        float* orow = o_buf + (size_t)(b * 128 + o) * ST + HALO + tb;
        if (tb + 3 < 1995) {
            *(float4*)orow = make_float4(vv[0], vv[1], vv[2], vv[3]);
        } else {
#pragma unroll
            for (int kk = 0; kk < 4; kk++)
                if (tb + kk < 1995) orow[kk] = vv[kk];
        }
    }
    __syncthreads();

    const int t = tid & 63, cg_ = tid >> 6;
    const float a1 = *a1_0;
    float acc2[8];
#pragma unroll
    for (int q = 0; q < 8; q++) acc2[q] = b1_0[cg_ * 8 + q];
    for (int C = 0; C < 128; C++) {
        const float ov = o_lds[C][t];
        const float4* wr = (const float4*)(w1T0 + (size_t)C * 32 + cg_ * 8);
        float4 w0 = wr[0], w1 = wr[1];
        acc2[0] = fmaf(w0.x, ov, acc2[0]); acc2[1] = fmaf(w0.y, ov, acc2[1]);
        acc2[2] = fmaf(w0.z, ov, acc2[2]); acc2[3] = fmaf(w0.w, ov, acc2[3]);
        acc2[4] = fmaf(w1.x, ov, acc2[4]); acc2[5] = fmaf(w1.y, ov, acc2[5]);
        acc2[6] = fmaf(w1.z, ov, acc2[6]); acc2[7] = fmaf(w1.w, ov, acc2[7]);
    }
    const int tt = t0 + t;
    if (tt < 1995) {
#pragma unroll
        for (int q = 0; q < 8; q++)
            g_out[(size_t)(b * 32 + cg_ * 8 + q) * ST + HALO + tt] = prelu_f(acc2[q], a1);
    }
}

// ---------------------------------------------------------------------------
// Fused TCN: LDS-resident g ping-pong, halo-only global traffic.
// Publish: relaxed flag store after __syncthreads vmcnt drain.
// ---------------------------------------------------------------------------
__device__ __forceinline__ void poll_acquire(const unsigned* flags, int b, int j,
                                             int k, unsigned target)
{
    int lo = j - k; if (lo < 0) lo = 0;
    int hi = j + k; if (hi > 31) hi = 31;
    for (int n = lo; n <= hi; n++) {
        if (n == j) continue;
        const unsigned* p = flags + ((b << 5) + n) * 16;
        while (__hip_atomic_load(p, __ATOMIC_RELAXED, __HIP_MEMORY_SCOPE_AGENT) < target)
            __builtin_amdgcn_s_sleep(2);
    }
    __builtin_amdgcn_fence(__ATOMIC_ACQUIRE, "agent");
}

__device__ __forceinline__ void store_pair_agent(float* dst, int trel, float v0, float v1)
{
    if (trel + 1 < 1995) {
        unsigned long long raw =
            ((unsigned long long)__float_as_uint(v1) << 32) | __float_as_uint(v0);
        __hip_atomic_store((unsigned long long*)dst, raw,
                           __ATOMIC_RELAXED, __HIP_MEMORY_SCOPE_AGENT);
    } else if (trel < 1995) {
        __hip_atomic_store(dst, v0, __ATOMIC_RELAXED, __HIP_MEMORY_SCOPE_AGENT);
    }
}

__global__ __launch_bounds__(512) void tcn_fused(
    float* __restrict__ g0, float* __restrict__ g1,
    float* __restrict__ g2, float* __restrict__ g3,
    float* __restrict__ o_buf,
    const float* __restrict__ dw_all, const float* __restrict__ db_all,
    const float* __restrict__ a2_all,
    const float* __restrict__ wsumT_all, const float* __restrict__ bsum_all,
    const float* __restrict__ w1T_all, const float* __restrict__ b1_all,
    const float* __restrict__ a1_all, unsigned* __restrict__ wflag)
{
    __shared__ __align__(16) float w_lds[8192];
    __shared__ __align__(16) float h_lds[32 * 68];
    __shared__ __align__(16) float o_lds[128 * 68];
    __shared__ __align__(16) float g_lds[2][32 * 68];
    __shared__ __align__(16) float halo_lds[32 * 260];
    const int tid = threadIdx.x;
    const int blk = blockIdx.x;
    const int b   = blk & 7;
    const int jt  = blk >> 3;
    const int t0  = jt * 64;
    float* gb[4] = { g0, g1, g2, g3 };

#pragma unroll
    for (int k = 0; k < 4; k++) {
        int n = tid + k * 512;
        int C = n >> 4, seg = n & 15;
        *(float4*)&o_lds[C * 68 + seg * 4] =
            *(const float4*)&o_buf[((size_t)(b * 128 + C)) * ST + HALO + t0 + seg * 4];
    }
    {
        int cc = tid >> 4, seg = tid & 15;
        *(float4*)&g_lds[0][cc * 68 + seg * 4] =
            *(const float4*)&g0[((size_t)(b * 32 + cc)) * ST + HALO + t0 + seg * 4];
    }

    for (int i = 0; i < 24; i++) {
        const int dil  = 1 << (i & 7);
        const int dil2 = (dil < 2) ? 2 : dil;
        const int k_rd = (dil > 64) ? 2 : 1;
        const float* gin_g = gb[i & 3];
        float* gout_g      = gb[(i + 1) & 3];
        float* gin_lds  = g_lds[i & 1];
        float* gout_lds = g_lds[(i + 1) & 1];

        {
            const float* wsum = wsumT_all + (size_t)i * 4096;
#pragma unroll
            for (int k = 0; k < 2; k++) {
                int n = tid + k * 512;
                *(float4*)&w_lds[n * 4] = *(const float4*)&wsum[n * 4];
            }
            if (i < 23) {
                const float* w1 = w1T_all + (size_t)(i + 1) * 4096;
#pragma unroll
                for (int k = 0; k < 2; k++) {
                    int n = tid + k * 512;
                    *(float4*)&w_lds[4096 + n * 4] = *(const float4*)&w1[n * 4];
                }
            }
        }

        if (i > 0 && tid == 0) poll_acquire(wflag, b, jt, k_rd, (unsigned)i);
        __syncthreads();

        // halo load: dsh covers dil2 up to 128 (7 bits) — r13 fix.
        {
            const int dsh = (dil2 >= 128) ? 7 : (dil2 >= 64) ? 6 : (dil2 >= 32) ? 5
                          : (dil2 >= 16) ? 4 : (dil2 >= 8) ? 3 : (dil2 >= 4) ? 2 : 1;
            const int total = 32 << dsh;
            for (int n = tid; n < total; n += 512) {
                const int cc = n >> dsh;
                const int pi = n & (dil2 - 1);
                const int hc = pi * 2;
                const int tg = (hc < dil2) ? (t0 - dil2 + hc) : (t0 + 64 + hc - dil2);
                float v0 = 0.f, v1 = 0.f;
                const float* src = gin_g + ((size_t)(b * 32 + cc)) * ST + HALO + tg;
                if (tg >= 0 && tg + 1 < 1995) {
                    unsigned long long raw = __hip_atomic_load(
                        (const unsigned long long*)src,
                        __ATOMIC_RELAXED, __HIP_MEMORY_SCOPE_AGENT);
                    v0 = __uint_as_float((unsigned)raw);
                    v1 = __uint_as_float((unsigned)(raw >> 32));
                } else {
                    if (tg >= 0 && tg < 1995)
                        v0 = __hip_atomic_load(src, __ATOMIC_RELAXED,
                                               __HIP_MEMORY_SCOPE_AGENT);
                    if (tg + 1 >= 0 && tg + 1 < 1995)
                        v1 = __hip_atomic_load(src + 1, __ATOMIC_RELAXED,
                                               __HIP_MEMORY_SCOPE_AGENT);
                }
                halo_lds[cc * 260 + hc]     = v0;
                halo_lds[cc * 260 + hc + 1] = v1;
            }
        }
        __syncthreads();

        {
            const float a2 = a2_all[i];
            const int t = tid & 63, cc0 = (tid >> 6) * 4;
            const int tt = t0 + t;
#pragma unroll
            for (int q = 0; q < 4; q++) {
                const int cc = cc0 + q;
                const float w0 = dw_all[i * 96 + cc * 3 + 0];
                const float w1v = dw_all[i * 96 + cc * 3 + 1];
                const float w2 = dw_all[i * 96 + cc * 3 + 2];
                const float ctr = gin_lds[cc * 68 + t];
                float lo = 0.f, hi = 0.f;
                const int tm = tt - dil;
                if (tm >= 0)
                    lo = (tm >= t0) ? gin_lds[cc * 68 + (tm - t0)]
                                    : halo_lds[cc * 260 + (tm - t0 + dil2)];
                const int tp = tt + dil;
                if (tp < 1995)
                    hi = (tp < t0 + 64) ? gin_lds[cc * 68 + (tp - t0)]
                                        : halo_lds[cc * 260 + (dil2 + tp - t0 - 64)];
                float s = db_all[i * 32 + cc] + w1v * ctr;
                s = fmaf(w0, lo, s);
                s = fmaf(w2, hi, s);
                h_lds[cc * 68 + t] = prelu_f(s, a2);
            }
        }
        __syncthreads();

        {
            const int c4 = tid & 31, t4 = tid >> 5;
            float s[4][4];
#pragma unroll
            for (int ci = 0; ci < 4; ci++)
#pragma unroll
                for (int tj = 0; tj < 4; tj++) s[ci][tj] = 0.f;
            for (int cc = 0; cc < 32; cc++) {
                float4 w4 = *(const float4*)&w_lds[cc * 128 + c4 * 4];
                float4 h4 = *(const float4*)&h_lds[cc * 68 + t4 * 4];
                const float wv[4] = {w4.x, w4.y, w4.z, w4.w};
                const float hv[4] = {h4.x, h4.y, h4.z, h4.w};
#pragma unroll
                for (int ci = 0; ci < 4; ci++)
#pragma unroll
                    for (int tj = 0; tj < 4; tj++)
                        s[ci][tj] = fmaf(wv[ci], hv[tj], s[ci][tj]);
            }
#pragma unroll
            for (int ci = 0; ci < 4; ci++) {
                const int C = c4 * 4 + ci;
                const float bs = bsum_all[i * 128 + C];
                float4 ov = *(float4*)&o_lds[C * 68 + t4 * 4];
                ov.x += s[ci][0] + bs;
                ov.y += s[ci][1] + bs;
                ov.z += s[ci][2] + bs;
                ov.w += s[ci][3] + bs;
                *(float4*)&o_lds[C * 68 + t4 * 4] = ov;
            }
        }

        if (i == 23) break;
        __syncthreads();

        {
            const int cc = tid & 31, tq = tid >> 5;
            const float a1 = a1_all[i + 1];
            const float b1v = b1_all[(i + 1) * 32 + cc];
            float acc2[4] = {b1v, b1v, b1v, b1v};
            for (int C = 0; C < 128; C++) {
                const float wv = w_lds[4096 + C * 32 + cc];
                float4 o4 = *(const float4*)&o_lds[C * 68 + tq * 4];
                acc2[0] = fmaf(wv, o4.x, acc2[0]);
                acc2[1] = fmaf(wv, o4.y, acc2[1]);
                acc2[2] = fmaf(wv, o4.z, acc2[2]);
                acc2[3] = fmaf(wv, o4.w, acc2[3]);
            }
#pragma unroll
            for (int kk = 0; kk < 4; kk++)
                gout_lds[cc * 68 + tq * 4 + kk] = prelu_f(acc2[kk], a1);
        }
        __syncthreads();

        {
            const int dnext = 1 << ((i + 1) & 7);
            int md2 = (dnext > 64) ? 64 : dnext;
            if (md2 < 2) md2 = 2;
            if (md2 >= 64) {
                for (int n = tid; n < 1024; n += 512) {
                    const int cc = n >> 5, pi = n & 31;
                    const int lt = pi * 2;
                    float* dst = gout_g + ((size_t)(b * 32 + cc)) * ST + HALO + t0 + lt;
                    store_pair_agent(dst, t0 + lt,
                                     gout_lds[cc * 68 + lt], gout_lds[cc * 68 + lt + 1]);
                }
            } else {
                const int msh = (md2 >= 32) ? 5 : (md2 >= 16) ? 4 : (md2 >= 8) ? 3
                              : (md2 >= 4) ? 2 : 1;
                const int total = 32 << msh;
                for (int n = tid; n < total; n += 512) {
                    const int cc = n >> msh;
                    const int pi = n & (md2 - 1);
                    const int hc = pi * 2;
                    const int lt = (hc < md2) ? hc : (64 - 2 * md2 + hc);
                    float* dst = gout_g + ((size_t)(b * 32 + cc)) * ST + HALO + t0 + lt;
                    store_pair_agent(dst, t0 + lt,
                                     gout_lds[cc * 68 + lt], gout_lds[cc * 68 + lt + 1]);
                }
            }
        }
        __syncthreads();   // vmcnt drain: write-through stores acked at coherence point

        if (tid == 0)
            __hip_atomic_store(&wflag[((b << 5) + jt) * 16], (unsigned)(i + 1),
                               __ATOMIC_RELAXED, __HIP_MEMORY_SCOPE_AGENT);
    }

    __syncthreads();
#pragma unroll
    for (int k = 0; k < 4; k++) {
        int n = tid + k * 512;
        int C = n >> 4, seg = n & 15;
        *(float4*)&o_buf[((size_t)(b * 128 + C)) * ST + HALO + t0 + seg * 4] =
            *(const float4*)&o_lds[C * 68 + seg * 4];
    }
}

// ---------------------------------------------------------------------------
// mask + multiply -> y bf16 [t][c] via LDS transpose. grid (32, 4, 8)
// ---------------------------------------------------------------------------
__global__ __launch_bounds__(256) void mask_kernel(
    const float* __restrict__ o_buf, const float* __restrict__ f2, u16* __restrict__ yh,
    const float* __restrict__ wT, const float* __restrict__ mb,
    const float* __restrict__ a_out_p)
{
    __shared__ __align__(16) char smem[65536];
    float (*o_lds)[64]  = (float (*)[64])smem;
    float (*w_lds)[256] = (float (*)[256])(smem + 32768);
    u16* tile = (u16*)smem;

    const int tid = threadIdx.x;
    const int t0  = blockIdx.x * 64;
    const int m0  = blockIdx.y * 256;
    const int b   = blockIdx.z;
    const float ao = *a_out_p;

#pragma unroll
    for (int r = 0; r < 8; r++) {
        int n4 = tid + r * 256;
        int C = n4 >> 4, p = n4 & 15;
        float4 v = *(const float4*)(o_buf + (size_t)(b * 128 + C) * ST + HALO + t0 + p * 4);
        v.x = prelu_f(v.x, ao); v.y = prelu_f(v.y, ao);
        v.z = prelu_f(v.z, ao); v.w = prelu_f(v.w, ao);
        *(float4*)(&o_lds[C][p * 4]) = v;
    }

    float acc[16][4];
#pragma unroll
    for (int i = 0; i < 16; i++)
#pragma unroll
        for (int k = 0; k < 4; k++) acc[i][k] = 0.f;
    const int tx = tid & 15, my = tid >> 4;

    for (int C0 = 0; C0 < 128; C0 += 32) {
#pragma unroll
        for (int r = 0; r < 8; r++) {
            int n4 = tid + r * 256;
            int c = n4 >> 6, m4 = n4 & 63;
            *(float4*)(&w_lds[c][m4 * 4]) =
                *(const float4*)(wT + (size_t)(C0 + c) * 1024 + m0 + m4 * 4);
        }
        __syncthreads();
#pragma unroll 2
        for (int c = 0; c < 32; c++) {
            float4 bv = *(const float4*)(&o_lds[C0 + c][tx * 4]);
            float a[16];
            *(float4*)(&a[0])  = *(const float4*)(&w_lds[c][my * 16 + 0]);
            *(float4*)(&a[4])  = *(const float4*)(&w_lds[c][my * 16 + 4]);
            *(float4*)(&a[8])  = *(const float4*)(&w_lds[c][my * 16 + 8]);
            *(float4*)(&a[12]) = *(const float4*)(&w_lds[c][my * 16 + 12]);
#pragma unroll
            for (int mm = 0; mm < 16; mm++) {
                acc[mm][0] = fmaf(a[mm], bv.x, acc[mm][0]);
                acc[mm][1] = fmaf(a[mm], bv.y, acc[mm][1]);
                acc[mm][2] = fmaf(a[mm], bv.z, acc[mm][2]);
                acc[mm][3] = fmaf(a[mm], bv.w, acc[mm][3]);
            }
        }
        __syncthreads();
    }

    const int tb = t0 + tx * 4;
#pragma unroll
    for (int mm = 0; mm < 16; mm++) {
        const int mi = m0 + my * 16 + mm;
        const float bb = mb[mi];
        const int F = mi & 511;
        const float* f2row = f2 + (size_t)(b * 512 + F) * ST + HALO + tb;
#pragma unroll
        for (int kk = 0; kk < 4; kk++) {
            const float mval = 1.f / (1.f + __expf(-(acc[mm][kk] + bb)));
            acc[mm][kk] = mval * f2row[kk];
        }
    }
#pragma unroll
    for (int kk = 0; kk < 4; kk++) {
        const int row = tx * 4 + kk;
#pragma unroll
        for (int half = 0; half < 2; half++) {
            union { u16 u[8]; uint4 v; } p;
#pragma unroll
            for (int q = 0; q < 8; q++) p.u[q] = f2b(acc[half * 8 + q][kk]);
            *(uint4*)&tile[row * 280 + my * 16 + half * 8] = p.v;
        }
    }
    __syncthreads();
    const int F0 = m0 & 511, sIdx = m0 >> 9;
    u16* ybase = yh + ((size_t)(b * 2 + sIdx) * TR) * 512;
    for (int i = tid; i < 2048; i += 256) {
        const int row = i >> 5, seg = i & 31;
        const int t = t0 + row;
        if (t < 1995)
            *(uint4*)&ybase[(size_t)(RHALO + t) * 512 + F0 + seg * 8] =
                *(const uint4*)&tile[row * 280 + seg * 8];
    }
}

// ---------------------------------------------------------------------------
// Decoder tconv3: 512->1, k16 s8. OOB taps read as 0. grid (63, 16)
// ---------------------------------------------------------------------------
__global__ __launch_bounds__(256) void dec3_kernel(
    const float* __restrict__ d2, const float* __restrict__ w3, float* __restrict__ out)
{
    __shared__ float tile[512][34];
    const int tid = threadIdx.x;
    const int bb  = blockIdx.y;
    const int tau0 = blockIdx.x * 256;
    const int tbase = (tau0 >> 3) - 1;
    const float* src = d2 + (size_t)bb * 512 * ST + HALO + tbase;
    for (int n = tid; n < 512 * 34; n += 256) {
        int o = n / 34, i = n % 34;
        const int tg = tbase + i;
        tile[o][i] = (tg >= 0 && tg < 1999) ? src[(size_t)o * ST + i] : 0.f;
    }
    __syncthreads();

    const int tau = tau0 + tid;
    if (tau >= 16000) return;
    const int k1 = tau & 7;
    const int t1l = (tid >> 3) + 1;
    float acc = 0.f;
#pragma unroll 8
    for (int o = 0; o < 512; o++) {
        acc = fmaf(tile[o][t1l],     w3[o * 16 + k1],     acc);
        acc = fmaf(tile[o][t1l - 1], w3[o * 16 + 8 + k1], acc);
    }
    const int p = bb >> 1, s = bb & 1;
    out[(size_t)(p * 2 + s) * 16000 + tau] = acc;
}

// ---------------------------------------------------------------------------
extern "C" void kernel_launch(void* const* d_in, const int* in_sizes, int n_in,
                              void* d_out, int out_size, void* d_ws, size_t ws_size,
                              hipStream_t stream)
{
    (void)in_sizes; (void)n_in; (void)out_size; (void)ws_size;
    float* ws  = (float*)d_ws;
    u16*   wsu = (u16*)d_ws;
    const float* x_real   = (const float*)d_in[0];
    const float* x_imag   = (const float*)d_in[1];
    const float* enc_w0   = (const float*)d_in[2];
    const float* enc_w1   = (const float*)d_in[3];
    const float* enc_w2   = (const float*)d_in[4];
    const float* enc_a    = (const float*)d_in[5];
    const float* mg_in_w  = (const float*)d_in[6];
    const float* mg_in_b  = (const float*)d_in[7];
    const float* blk_w1   = (const float*)d_in[8];
    const float* blk_b1   = (const float*)d_in[9];
    const float* blk_a1   = (const float*)d_in[10];
    const float* blk_dw   = (const float*)d_in[11];
    const float* blk_db   = (const float*)d_in[12];
    const float* blk_a2   = (const float*)d_in[13];
    const float* blk_rw   = (const float*)d_in[14];
    const float* blk_rb   = (const float*)d_in[15];
    const float* blk_sw   = (const float*)d_in[16];
    const float* blk_sb   = (const float*)d_in[17];
    const float* mg_out_a = (const float*)d_in[18];
    const float* mg_out_w = (const float*)d_in[19];
    const float* mg_out_b = (const float*)d_in[20];
    const float* dec_w1   = (const float*)d_in[21];
    const float* dec_w2   = (const float*)d_in[22];
    const float* dec_a    = (const float*)d_in[23];
    const float* dec_w3   = (const float*)d_in[24];
    float* out = (float*)d_out;

    u16*   f0h   = wsu + U_F0H;
    u16*   f1h   = wsu + U_F1H;
    float* f2    = ws  + F_F2;
    float* d2    = ws  + F_D2;
    u16*   yh    = wsu + U_YH;
    u16*   d1h   = wsu + U_D1H;
    float* obuf  = ws  + F_O;
    float* g0    = ws  + F_G0;
    float* g1    = ws  + F_G1;
    float* g2    = ws  + F_G2;
    float* g3    = ws  + F_G3;
    float* WF    = ws  + F_W;
    u16*   WB    = wsu + U_WB;
    unsigned* flags = (unsigned*)(ws + F_FLAG);

    const dim3 blk(256);

    prep_all<<<dim3(64, 11), blk, 0, stream>>>(enc_w1, enc_w2, dec_w1, dec_w2,
        mg_in_w, mg_out_w, blk_w1, blk_rw, blk_rb, blk_sw, blk_sb, ws, wsu, flags);

    enc0_kernel<<<dim3(8, 64, 8), blk, 0, stream>>>(x_real, x_imag, enc_w0, f0h);

    conv_mfma<0, 0><<<dim3(16, 4, 8), blk, 0, stream>>>(
        f0h, f1h, nullptr, WB + 0 * 786432, enc_a + 0, 1997);
    conv_mfma<0, 1><<<dim3(16, 4, 8), blk, 0, stream>>>(
        f1h, nullptr, f2, WB + 1 * 786432, enc_a + 1, 1995);

    mgin_kernel<<<dim3(32, 8), blk, 0, stream>>>(f2, obuf, g0, WF + W_MGIN, mg_in_b,
        WF + W_W1T, blk_b1, blk_a1);

    {
        const float* dwp   = blk_dw;
        const float* dbp   = blk_db;
        const float* a2p   = blk_a2;
        const float* wsump = WF + W_WSUMT;
        const float* bsump = WF + W_BSUM;
        const float* w1p   = WF + W_W1T;
        const float* b1p   = blk_b1;
        const float* a1p   = blk_a1;
        unsigned* flg = flags;
        void* args[] = { &g0, &g1, &g2, &g3, &obuf,
                         (void*)&dwp, (void*)&dbp, (void*)&a2p,
                         (void*)&wsump, (void*)&bsump, (void*)&w1p,
                         (void*)&b1p, (void*)&a1p, &flg };
        (void)hipLaunchCooperativeKernel((void*)tcn_fused, dim3(256), dim3(512),
                                         args, 0, stream);
    }

    mask_kernel<<<dim3(32, 4, 8), blk, 0, stream>>>(obuf, f2, yh,
        WF + W_MGOUT, mg_out_b, mg_out_a);

    conv_mfma<-2, 0><<<dim3(16, 4, 16), blk, 0, stream>>>(
        yh, d1h, nullptr, WB + 2 * 786432, dec_a + 0, 1997);
    conv_mfma<-2, 1><<<dim3(16, 4, 16), blk, 0, stream>>>(
        d1h, nullptr, d2, WB + 3 * 786432, dec_a + 1, 1999);

    dec3_kernel<<<dim3(63, 16), blk, 0, stream>>>(d2, dec_w3, out);
}